// Round 1
// baseline (2276.758 us; speedup 1.0000x reference)
//
#include <hip/hip_runtime.h>
#include <hip/hip_bf16.h>

// Problem constants
#define B_   64
#define C_   3129
#define K_   10
#define DF_  768
#define F_   676      // 26*26
#define V_   10000
#define DW_  300
#define DT_  1024
#define CHUNK_B 8
#define N_CHUNKS 8

// ---------------------------------------------------------------------------
// 1. top-k (K=10) per row of logits [B, C], exact lax.top_k order:
//    descending value, lowest index on ties.
__global__ void topk_kernel(const float* __restrict__ logits,
                            int* __restrict__ topk_idx) {
    __shared__ float vals[C_];
    __shared__ float red_v[256];
    __shared__ int   red_i[256];
    int b = blockIdx.x;
    int tid = threadIdx.x;
    for (int i = tid; i < C_; i += 256) vals[i] = logits[(size_t)b * C_ + i];
    __syncthreads();
    for (int sel = 0; sel < K_; ++sel) {
        float bv = -INFINITY; int bi = 0x7fffffff;
        for (int i = tid; i < C_; i += 256) {
            float v = vals[i];
            if (v > bv) { bv = v; bi = i; }   // strict > keeps lowest index
        }
        red_v[tid] = bv; red_i[tid] = bi;
        __syncthreads();
        for (int s = 128; s > 0; s >>= 1) {
            if (tid < s) {
                float ov = red_v[tid + s]; int oi = red_i[tid + s];
                if (ov > red_v[tid] || (ov == red_v[tid] && oi < red_i[tid])) {
                    red_v[tid] = ov; red_i[tid] = oi;
                }
            }
            __syncthreads();
        }
        if (tid == 0) {
            topk_idx[b * K_ + sel] = red_i[0];
            vals[red_i[0]] = -INFINITY;
        }
        __syncthreads();
    }
}

// ---------------------------------------------------------------------------
// 2. emb[b,k,:] = mean over 4 of word2vec[indices_table[topk_idx[b,k]]]
__global__ void emb_kernel(const int* __restrict__ topk_idx,
                           const int* __restrict__ indices_table,
                           const float* __restrict__ word2vec,
                           float* __restrict__ emb) {
    int idx = blockIdx.x * blockDim.x + threadIdx.x;
    if (idx >= B_ * K_ * DW_) return;
    int j  = idx % DW_;
    int bk = idx / DW_;
    int cls = topk_idx[bk];
    const int* tbl = indices_table + (size_t)cls * 4;
    float s = 0.f;
    #pragma unroll
    for (int i = 0; i < 4; ++i) s += word2vec[(size_t)tbl[i] * DW_ + j];
    emb[idx] = s * 0.25f;
}

// ---------------------------------------------------------------------------
// Generic fp32 GEMM: C[M,N] = act(A[M,Kd] @ B[Kd,N] + bias), 64x64 tile.
// Requires M % 64 == 0, N % 64 == 0, Kd % 4 == 0.
template <int RELU>
__global__ __launch_bounds__(256)
void gemm_bias(const float* __restrict__ A, const float* __restrict__ Bm,
               const float* __restrict__ bias, float* __restrict__ Cm,
               int Mn, int Nn, int Kd) {
    __shared__ float As[64][17];   // padded: avoids 16-way bank conflict
    __shared__ float Bs[16][64];
    int tid = threadIdx.x;
    int tx = tid & 15, ty = tid >> 4;
    int r0 = blockIdx.x * 64, c0 = blockIdx.y * 64;
    float acc[4][4] = {};
    for (int k0 = 0; k0 < Kd; k0 += 16) {
        int rr = tid >> 2, kk4 = (tid & 3) * 4;
        float4 a4 = make_float4(0.f, 0.f, 0.f, 0.f);
        if (k0 + kk4 < Kd)
            a4 = *(const float4*)(A + (size_t)(r0 + rr) * Kd + k0 + kk4);
        As[rr][kk4 + 0] = a4.x; As[rr][kk4 + 1] = a4.y;
        As[rr][kk4 + 2] = a4.z; As[rr][kk4 + 3] = a4.w;
        int kk = tid >> 4, cc4 = (tid & 15) * 4;
        float4 b4 = make_float4(0.f, 0.f, 0.f, 0.f);
        if (k0 + kk < Kd)
            b4 = *(const float4*)(Bm + (size_t)(k0 + kk) * Nn + c0 + cc4);
        *(float4*)&Bs[kk][cc4] = b4;
        __syncthreads();
        #pragma unroll
        for (int kki = 0; kki < 16; ++kki) {
            float bv[4];
            *(float4*)bv = *(const float4*)&Bs[kki][tx * 4];
            float av[4];
            #pragma unroll
            for (int u = 0; u < 4; ++u) av[u] = As[ty * 4 + u][kki];
            #pragma unroll
            for (int u = 0; u < 4; ++u)
                #pragma unroll
                for (int w = 0; w < 4; ++w)
                    acc[u][w] += av[u] * bv[w];
        }
        __syncthreads();
    }
    #pragma unroll
    for (int u = 0; u < 4; ++u) {
        int r = r0 + ty * 4 + u;
        #pragma unroll
        for (int w = 0; w < 4; ++w) {
            int c = c0 + tx * 4 + w;
            float v = acc[u][w] + bias[c];
            if (RELU) v = fmaxf(v, 0.f);
            Cm[(size_t)r * Nn + c] = v;
        }
    }
}

// ---------------------------------------------------------------------------
// 3. v[bc,f,d] = relu( sum_kd ftm[b0+bc, kd, f] * W_v[kd, d] + b_v[d] )
//    A is read transposed (ftm layout [b][kd][f], f contiguous).
__global__ __launch_bounds__(256)
void gemm_v_kernel(const float* __restrict__ ftm, const float* __restrict__ Wv,
                   const float* __restrict__ bv, float* __restrict__ v_buf,
                   int b0) {
    __shared__ float As[16][64];   // [kk][f]  (natural transposed layout)
    __shared__ float Bs[16][64];   // [kk][d]
    int tid = threadIdx.x;
    int tx = tid & 15, ty = tid >> 4;
    int r0 = blockIdx.x * 64;      // f tile (11 tiles, last partial: 676)
    int c0 = blockIdx.y * 64;      // d tile (16 tiles)
    int bc = blockIdx.z;
    int b = b0 + bc;
    const float* fbase = ftm + (size_t)b * DF_ * F_;
    float acc[4][4] = {};
    for (int k0 = 0; k0 < DF_; k0 += 16) {
        int kk = tid >> 4, rr4 = (tid & 15) * 4;
        float4 a4 = make_float4(0.f, 0.f, 0.f, 0.f);
        if (r0 + rr4 < F_)   // F_ % 4 == 0 so whole float4 in/out of bounds
            a4 = *(const float4*)(fbase + (size_t)(k0 + kk) * F_ + r0 + rr4);
        *(float4*)&As[kk][rr4] = a4;
        float4 b4 = *(const float4*)(Wv + (size_t)(k0 + kk) * DT_ + c0 + rr4);
        *(float4*)&Bs[kk][rr4] = b4;
        __syncthreads();
        #pragma unroll
        for (int kki = 0; kki < 16; ++kki) {
            float av[4], bvv[4];
            *(float4*)av  = *(const float4*)&As[kki][ty * 4];
            *(float4*)bvv = *(const float4*)&Bs[kki][tx * 4];
            #pragma unroll
            for (int u = 0; u < 4; ++u)
                #pragma unroll
                for (int w = 0; w < 4; ++w)
                    acc[u][w] += av[u] * bvv[w];
        }
        __syncthreads();
    }
    #pragma unroll
    for (int u = 0; u < 4; ++u) {
        int r = r0 + ty * 4 + u;   // f position
        if (r < F_) {
            #pragma unroll
            for (int w = 0; w < 4; ++w) {
                int c = c0 + tx * 4 + w;
                v_buf[((size_t)(bc * F_ + r)) * DT_ + c] =
                    fmaxf(acc[u][w] + bv[c], 0.f);
            }
        }
    }
}

// ---------------------------------------------------------------------------
// 4. s[bc,f,k] = sum_d v[bc,f,d] * cls_emb[b0+bc,k,d]
//    One wave (64 lanes) per (bc,f); 16 d's per lane.
__global__ __launch_bounds__(256)
void attn_s_kernel(const float* __restrict__ v_buf,
                   const float* __restrict__ cls_emb,
                   float* __restrict__ s_buf, int b0) {
    int tid = threadIdx.x;
    int wave = tid >> 6, lane = tid & 63;
    int bc = blockIdx.y;
    int f = blockIdx.x * 4 + wave;   // 169*4 == 676 exactly
    const float* vp = v_buf + ((size_t)(bc * F_ + f)) * DT_ + lane * 16;
    float vv[16];
    #pragma unroll
    for (int i = 0; i < 4; ++i) *(float4*)&vv[i * 4] = *(const float4*)(vp + i * 4);
    const float* cp = cls_emb + ((size_t)(b0 + bc) * K_) * DT_ + lane * 16;
    #pragma unroll
    for (int k = 0; k < K_; ++k) {
        const float* c = cp + (size_t)k * DT_;
        float cc[16];
        #pragma unroll
        for (int i = 0; i < 4; ++i) *(float4*)&cc[i * 4] = *(const float4*)(c + i * 4);
        float acc = 0.f;
        #pragma unroll
        for (int i = 0; i < 16; ++i) acc += vv[i] * cc[i];
        #pragma unroll
        for (int off = 32; off > 0; off >>= 1) acc += __shfl_down(acc, off);
        if (lane == 0) s_buf[((size_t)(bc * F_) + f) * K_ + k] = acc;
    }
}

// ---------------------------------------------------------------------------
// 5. softmax over f per (bc,k): attw[bc,f,k] = softmax_f(s[bc,f,k])
__global__ void softmax_kernel(const float* __restrict__ s_buf,
                               float* __restrict__ attw) {
    int k = blockIdx.x, bc = blockIdx.y, tid = threadIdx.x;
    __shared__ float red[256];
    const float* sp = s_buf + (size_t)bc * F_ * K_ + k;
    float m = -INFINITY;
    for (int f = tid; f < F_; f += 256) m = fmaxf(m, sp[(size_t)f * K_]);
    red[tid] = m; __syncthreads();
    for (int s = 128; s > 0; s >>= 1) {
        if (tid < s) red[tid] = fmaxf(red[tid], red[tid + s]);
        __syncthreads();
    }
    m = red[0]; __syncthreads();
    float l = 0.f;
    for (int f = tid; f < F_; f += 256) l += __expf(sp[(size_t)f * K_] - m);
    red[tid] = l; __syncthreads();
    for (int s = 128; s > 0; s >>= 1) {
        if (tid < s) red[tid] += red[tid + s];
        __syncthreads();
    }
    l = red[0];
    float rl = 1.f / l;
    float* wp = attw + (size_t)bc * F_ * K_ + k;
    for (int f = tid; f < F_; f += 256) wp[(size_t)f * K_] = __expf(sp[(size_t)f * K_] - m) * rl;
}

// ---------------------------------------------------------------------------
// 6. o[k,d] = sum_f attw[bc,f,k] * v[bc,f,d]; bap[b,d] = sum_k o[k,d]*cls[b,k,d]
__global__ __launch_bounds__(128)
void o_bap_kernel(const float* __restrict__ v_buf,
                  const float* __restrict__ attw,
                  const float* __restrict__ cls_emb,
                  float* __restrict__ bap, int b0) {
    int tid = threadIdx.x;     // 128
    int dt = blockIdx.x;       // 8 tiles of 128 d
    int bc = blockIdx.y;
    int d = dt * 128 + tid;
    int b = b0 + bc;
    __shared__ float wbuf[32 * K_];
    float acc[K_] = {};
    for (int fb = 0; fb < F_; fb += 32) {
        int nf = min(32, F_ - fb);
        for (int j = tid; j < nf * K_; j += 128)
            wbuf[j] = attw[((size_t)(bc * F_ + fb)) * K_ + j];
        __syncthreads();
        for (int ff = 0; ff < nf; ++ff) {
            float vv = v_buf[((size_t)(bc * F_ + fb + ff)) * DT_ + d];
            #pragma unroll
            for (int k = 0; k < K_; ++k) acc[k] += wbuf[ff * K_ + k] * vv;
        }
        __syncthreads();
    }
    float bsum = 0.f;
    #pragma unroll
    for (int k = 0; k < K_; ++k)
        bsum += acc[k] * cls_emb[((size_t)b * K_ + k) * DT_ + d];
    bap[(size_t)b * DT_ + d] = bsum;
}

// ---------------------------------------------------------------------------
// 7. lg[b,k] = y[b,:] @ W_fc[:,k] + b_fc[k]; scatter into out[b, topk_idx[b,k]]
__global__ void final_kernel(const float* __restrict__ y,
                             const float* __restrict__ Wfc,
                             const float* __restrict__ bfc,
                             const int* __restrict__ topk_idx,
                             float* __restrict__ out) {
    int b = blockIdx.x, tid = threadIdx.x;
    int lane = tid & 63, wave = tid >> 6;
    float pk[K_] = {};
    for (int d = tid; d < DT_; d += 256) {
        float yv = y[(size_t)b * DT_ + d];
        #pragma unroll
        for (int k = 0; k < K_; ++k) pk[k] += yv * Wfc[(size_t)d * K_ + k];
    }
    __shared__ float wsum[4][K_];
    #pragma unroll
    for (int k = 0; k < K_; ++k) {
        float a = pk[k];
        #pragma unroll
        for (int off = 32; off > 0; off >>= 1) a += __shfl_down(a, off);
        if (lane == 0) wsum[wave][k] = a;
    }
    __syncthreads();
    if (tid < K_) {
        float lg = wsum[0][tid] + wsum[1][tid] + wsum[2][tid] + wsum[3][tid] + bfc[tid];
        out[(size_t)b * C_ + topk_idx[b * K_ + tid]] = lg;
    }
}

// ---------------------------------------------------------------------------
extern "C" void kernel_launch(void* const* d_in, const int* in_sizes, int n_in,
                              void* d_out, int out_size, void* d_ws, size_t ws_size,
                              hipStream_t stream) {
    const float* ftm           = (const float*)d_in[0];
    const float* logits        = (const float*)d_in[1];
    // d_in[2] = labels (unused by reference)
    const int*   indices_table = (const int*)d_in[3];
    const float* word2vec      = (const float*)d_in[4];
    const float* W_emb         = (const float*)d_in[5];
    const float* b_emb         = (const float*)d_in[6];
    const float* W_cls         = (const float*)d_in[7];
    const float* b_cls         = (const float*)d_in[8];
    const float* W_v           = (const float*)d_in[9];
    const float* b_v           = (const float*)d_in[10];
    const float* W_bap         = (const float*)d_in[11];
    const float* b_bap         = (const float*)d_in[12];
    const float* W_fc          = (const float*)d_in[13];
    const float* b_fc          = (const float*)d_in[14];
    float* out = (float*)d_out;

    char* ws = (char*)d_ws;
    size_t off = 0;
    auto alloc = [&](size_t bytes) -> void* {
        void* p = ws + off;
        off = (off + bytes + 255) & ~(size_t)255;
        return p;
    };
    int*   topk_idx = (int*)  alloc((size_t)B_ * K_ * 4);
    float* emb      = (float*)alloc((size_t)B_ * K_ * DW_ * 4);
    float* cls1     = (float*)alloc((size_t)B_ * K_ * DT_ * 4);
    float* cls2     = (float*)alloc((size_t)B_ * K_ * DT_ * 4);
    float* v_buf    = (float*)alloc((size_t)CHUNK_B * F_ * DT_ * 4);
    float* s_buf    = (float*)alloc((size_t)CHUNK_B * F_ * K_ * 4);
    float* attw     = (float*)alloc((size_t)CHUNK_B * F_ * K_ * 4);
    float* bap      = (float*)alloc((size_t)B_ * DT_ * 4);
    float* yb       = (float*)alloc((size_t)B_ * DT_ * 4);

    hipMemsetAsync(d_out, 0, (size_t)out_size * sizeof(float), stream);

    topk_kernel<<<B_, 256, 0, stream>>>(logits, topk_idx);
    emb_kernel<<<(B_ * K_ * DW_ + 255) / 256, 256, 0, stream>>>(
        topk_idx, indices_table, word2vec, emb);
    gemm_bias<1><<<dim3(B_ * K_ / 64, DT_ / 64), 256, 0, stream>>>(
        emb, W_emb, b_emb, cls1, B_ * K_, DT_, DW_);
    gemm_bias<1><<<dim3(B_ * K_ / 64, DT_ / 64), 256, 0, stream>>>(
        cls1, W_cls, b_cls, cls2, B_ * K_, DT_, DT_);

    for (int c = 0; c < N_CHUNKS; ++c) {
        int b0 = c * CHUNK_B;
        gemm_v_kernel<<<dim3((F_ + 63) / 64, DT_ / 64, CHUNK_B), 256, 0, stream>>>(
            ftm, W_v, b_v, v_buf, b0);
        attn_s_kernel<<<dim3(F_ / 4, CHUNK_B), 256, 0, stream>>>(
            v_buf, cls2, s_buf, b0);
        softmax_kernel<<<dim3(K_, CHUNK_B), 256, 0, stream>>>(s_buf, attw);
        o_bap_kernel<<<dim3(DT_ / 128, CHUNK_B), 128, 0, stream>>>(
            v_buf, attw, cls2, bap, b0);
    }

    gemm_bias<1><<<dim3(B_ / 64, DT_ / 64), 256, 0, stream>>>(
        bap, W_bap, b_bap, yb, B_, DT_, DT_);
    final_kernel<<<B_, 256, 0, stream>>>(yb, W_fc, b_fc, topk_idx, out);
}

// Round 2
// 1489.042 us; speedup vs baseline: 1.5290x; 1.5290x over previous
//
#include <hip/hip_runtime.h>
#include <hip/hip_bf16.h>

// Problem constants
#define B_   64
#define C_   3129
#define K_   10
#define DF_  768
#define F_   676      // 26*26
#define V_   10000
#define DW_  300
#define DT_  1024
#define CHUNK_B 8
#define N_CHUNKS 8

typedef __attribute__((ext_vector_type(8))) short short8;   // 8 bf16 (4 VGPRs)
typedef __attribute__((ext_vector_type(4))) float floatx4;  // 4 fp32

// ---------------------------------------------------------------------------
// 1. top-k (K=10) per row of logits [B, C], exact lax.top_k order.
__global__ void topk_kernel(const float* __restrict__ logits,
                            int* __restrict__ topk_idx) {
    __shared__ float vals[C_];
    __shared__ float red_v[256];
    __shared__ int   red_i[256];
    int b = blockIdx.x;
    int tid = threadIdx.x;
    for (int i = tid; i < C_; i += 256) vals[i] = logits[(size_t)b * C_ + i];
    __syncthreads();
    for (int sel = 0; sel < K_; ++sel) {
        float bv = -INFINITY; int bi = 0x7fffffff;
        for (int i = tid; i < C_; i += 256) {
            float v = vals[i];
            if (v > bv) { bv = v; bi = i; }
        }
        red_v[tid] = bv; red_i[tid] = bi;
        __syncthreads();
        for (int s = 128; s > 0; s >>= 1) {
            if (tid < s) {
                float ov = red_v[tid + s]; int oi = red_i[tid + s];
                if (ov > red_v[tid] || (ov == red_v[tid] && oi < red_i[tid])) {
                    red_v[tid] = ov; red_i[tid] = oi;
                }
            }
            __syncthreads();
        }
        if (tid == 0) {
            topk_idx[b * K_ + sel] = red_i[0];
            vals[red_i[0]] = -INFINITY;
        }
        __syncthreads();
    }
}

// ---------------------------------------------------------------------------
// 2. emb[b,k,:] = mean over 4 of word2vec[indices_table[topk_idx[b,k]]]
__global__ void emb_kernel(const int* __restrict__ topk_idx,
                           const int* __restrict__ indices_table,
                           const float* __restrict__ word2vec,
                           float* __restrict__ emb) {
    int idx = blockIdx.x * blockDim.x + threadIdx.x;
    if (idx >= B_ * K_ * DW_) return;
    int j  = idx % DW_;
    int bk = idx / DW_;
    int cls = topk_idx[bk];
    const int* tbl = indices_table + (size_t)cls * 4;
    float s = 0.f;
    #pragma unroll
    for (int i = 0; i < 4; ++i) s += word2vec[(size_t)tbl[i] * DW_ + j];
    emb[idx] = s * 0.25f;
}

// ---------------------------------------------------------------------------
// Generic fp32 GEMM (small cls/bap path): C = act(A@B + bias), 64x64 tile.
template <int RELU>
__global__ __launch_bounds__(256)
void gemm_bias(const float* __restrict__ A, const float* __restrict__ Bm,
               const float* __restrict__ bias, float* __restrict__ Cm,
               int Mn, int Nn, int Kd) {
    __shared__ float As[64][17];
    __shared__ float Bs[16][64];
    int tid = threadIdx.x;
    int tx = tid & 15, ty = tid >> 4;
    int r0 = blockIdx.x * 64, c0 = blockIdx.y * 64;
    float acc[4][4] = {};
    for (int k0 = 0; k0 < Kd; k0 += 16) {
        int rr = tid >> 2, kk4 = (tid & 3) * 4;
        float4 a4 = make_float4(0.f, 0.f, 0.f, 0.f);
        if (k0 + kk4 < Kd)
            a4 = *(const float4*)(A + (size_t)(r0 + rr) * Kd + k0 + kk4);
        As[rr][kk4 + 0] = a4.x; As[rr][kk4 + 1] = a4.y;
        As[rr][kk4 + 2] = a4.z; As[rr][kk4 + 3] = a4.w;
        int kk = tid >> 4, cc4 = (tid & 15) * 4;
        float4 b4 = make_float4(0.f, 0.f, 0.f, 0.f);
        if (k0 + kk < Kd)
            b4 = *(const float4*)(Bm + (size_t)(k0 + kk) * Nn + c0 + cc4);
        *(float4*)&Bs[kk][cc4] = b4;
        __syncthreads();
        #pragma unroll
        for (int kki = 0; kki < 16; ++kki) {
            float bv[4];
            *(float4*)bv = *(const float4*)&Bs[kki][tx * 4];
            float av[4];
            #pragma unroll
            for (int u = 0; u < 4; ++u) av[u] = As[ty * 4 + u][kki];
            #pragma unroll
            for (int u = 0; u < 4; ++u)
                #pragma unroll
                for (int w = 0; w < 4; ++w)
                    acc[u][w] += av[u] * bv[w];
        }
        __syncthreads();
    }
    #pragma unroll
    for (int u = 0; u < 4; ++u) {
        int r = r0 + ty * 4 + u;
        #pragma unroll
        for (int w = 0; w < 4; ++w) {
            int c = c0 + tx * 4 + w;
            float v = acc[u][w] + bias[c];
            if (RELU) v = fmaxf(v, 0.f);
            Cm[(size_t)r * Nn + c] = v;
        }
    }
}

// ---------------------------------------------------------------------------
// Transpose + fp32->bf16 convert: src[rows][cols] fp32 -> dst[cols][rows] bf16.
// Used for ftm chunk ([kd][f] -> [f][kd]) and W_v ([kd][d] -> [d][kd]).
// rows % 64 == 0 required; cols % 4 == 0 required (cols may be ragged vs 64).
__global__ __launch_bounds__(256)
void transpose_cvt(const float* __restrict__ src, __hip_bfloat16* __restrict__ dst,
                   int rows, int cols, size_t src_bstride, size_t dst_bstride) {
    __shared__ float tile[64][65];
    const float* s = src + (size_t)blockIdx.z * src_bstride;
    __hip_bfloat16* d = dst + (size_t)blockIdx.z * dst_bstride;
    int c0 = blockIdx.x * 64;
    int r0 = blockIdx.y * 64;
    int t = threadIdx.x;
    int cl = (t & 15) * 4;
    int rl = t >> 4;
    #pragma unroll
    for (int i = 0; i < 4; ++i) {
        int r = rl + i * 16;
        float4 v = make_float4(0.f, 0.f, 0.f, 0.f);
        if (c0 + cl < cols)
            v = *(const float4*)(s + (size_t)(r0 + r) * cols + c0 + cl);
        tile[r][cl + 0] = v.x; tile[r][cl + 1] = v.y;
        tile[r][cl + 2] = v.z; tile[r][cl + 3] = v.w;
    }
    __syncthreads();
    int cw = t >> 2;            // col within tile (dst row)
    int r4 = (t & 3) * 16;      // dst col offset
    if (c0 + cw < cols) {
        __align__(16) __hip_bfloat16 buf[16];
        #pragma unroll
        for (int j = 0; j < 16; ++j) buf[j] = (__hip_bfloat16)tile[r4 + j][cw];
        float4* dp = (float4*)(d + (size_t)(c0 + cw) * rows + r0 + r4);
        dp[0] = *(float4*)&buf[0];
        dp[1] = *(float4*)&buf[8];
    }
}

// ---------------------------------------------------------------------------
// 3. MFMA bf16 GEMM: v[bc,f,d] = relu( A[bc,f,:] @ Wt[d,:] + bv[d] ), bf16 out.
//    A: [CHUNK_B][F_][DF_] bf16 (pre-transposed ftm), Wt: [DT_][DF_] bf16.
//    128x128 tile, BK=32, 2x2 waves x (4x4 of 16x16x32 frags).
#define PAD_K 40    // 32 + 8 pad, keeps 16B alignment, breaks bank conflicts
__global__ __launch_bounds__(256)
void gemm_v_mfma(const __hip_bfloat16* __restrict__ At,
                 const __hip_bfloat16* __restrict__ Wt,
                 const float* __restrict__ bv,
                 __hip_bfloat16* __restrict__ v_buf) {
    __shared__ __align__(16) __hip_bfloat16 As[128 * PAD_K];
    __shared__ __align__(16) __hip_bfloat16 Bs[128 * PAD_K];
    int tid = threadIdx.x;
    int wave = tid >> 6, lane = tid & 63;
    int quad = lane >> 4, l16 = lane & 15;
    int wm = (wave & 1) * 64, wn = (wave >> 1) * 64;
    int m0 = blockIdx.x * 128;   // f tile (6 tiles; guard at 676)
    int n0 = blockIdx.y * 128;   // d tile (8 tiles)
    int bc = blockIdx.z;
    const __hip_bfloat16* Ab = At + (size_t)bc * F_ * DF_;

    floatx4 acc[4][4];
    #pragma unroll
    for (int i = 0; i < 4; ++i)
        #pragma unroll
        for (int j = 0; j < 4; ++j)
            acc[i][j] = (floatx4){0.f, 0.f, 0.f, 0.f};

    // staging map: 512 16B-chunks per tile; thread t covers chunks t, t+256
    int row_a0 = tid >> 2, half = tid & 3;   // rows 0..63 (+64 on 2nd)

    for (int k0 = 0; k0 < DF_; k0 += 32) {
        #pragma unroll
        for (int i = 0; i < 2; ++i) {
            int row = row_a0 + i * 64;
            int f = m0 + row;
            float4 a4 = make_float4(0.f, 0.f, 0.f, 0.f);
            if (f < F_)
                a4 = *(const float4*)(Ab + (size_t)f * DF_ + k0 + half * 8);
            *(float4*)&As[row * PAD_K + half * 8] = a4;
            int n = n0 + row;
            float4 b4 = *(const float4*)(Wt + (size_t)n * DF_ + k0 + half * 8);
            *(float4*)&Bs[row * PAD_K + half * 8] = b4;
        }
        __syncthreads();
        short8 af[4], bf[4];
        #pragma unroll
        for (int mi = 0; mi < 4; ++mi)
            af[mi] = *(const short8*)&As[(wm + mi * 16 + l16) * PAD_K + quad * 8];
        #pragma unroll
        for (int ni = 0; ni < 4; ++ni)
            bf[ni] = *(const short8*)&Bs[(wn + ni * 16 + l16) * PAD_K + quad * 8];
        #pragma unroll
        for (int mi = 0; mi < 4; ++mi)
            #pragma unroll
            for (int ni = 0; ni < 4; ++ni)
                acc[mi][ni] = __builtin_amdgcn_mfma_f32_16x16x32_bf16(
                    af[mi], bf[ni], acc[mi][ni], 0, 0, 0);
        __syncthreads();
    }

    // epilogue: C/D mapping col=lane&15, row=quad*4+reg  [measured m89/m91]
    float bn[4];
    #pragma unroll
    for (int ni = 0; ni < 4; ++ni) bn[ni] = bv[n0 + wn + ni * 16 + l16];
    #pragma unroll
    for (int mi = 0; mi < 4; ++mi) {
        #pragma unroll
        for (int r = 0; r < 4; ++r) {
            int f = m0 + wm + mi * 16 + quad * 4 + r;
            if (f < F_) {
                size_t base = ((size_t)(bc * F_ + f)) * DT_;
                #pragma unroll
                for (int ni = 0; ni < 4; ++ni) {
                    int n = n0 + wn + ni * 16 + l16;
                    float val = acc[mi][ni][r] + bn[ni];
                    v_buf[base + n] = (__hip_bfloat16)fmaxf(val, 0.f);
                }
            }
        }
    }
}

// ---------------------------------------------------------------------------
// 4. s[bc,f,k] = sum_d v[bc,f,d] * cls_emb[b0+bc,k,d]   (v is bf16)
__global__ __launch_bounds__(256)
void attn_s_kernel(const __hip_bfloat16* __restrict__ v_buf,
                   const float* __restrict__ cls_emb,
                   float* __restrict__ s_buf, int b0) {
    int tid = threadIdx.x;
    int wave = tid >> 6, lane = tid & 63;
    int bc = blockIdx.y;
    int f = blockIdx.x * 4 + wave;   // 169*4 == 676
    union U { float4 f4; __hip_bfloat16 h[8]; };
    const float4* vp = (const float4*)(v_buf + ((size_t)(bc * F_ + f)) * DT_ + lane * 16);
    U u0, u1; u0.f4 = vp[0]; u1.f4 = vp[1];
    float vv[16];
    #pragma unroll
    for (int i = 0; i < 8; ++i) { vv[i] = (float)u0.h[i]; vv[8 + i] = (float)u1.h[i]; }
    const float* cp = cls_emb + ((size_t)(b0 + bc) * K_) * DT_ + lane * 16;
    #pragma unroll
    for (int k = 0; k < K_; ++k) {
        const float* c = cp + (size_t)k * DT_;
        float cc[16];
        #pragma unroll
        for (int i = 0; i < 4; ++i) *(float4*)&cc[i * 4] = *(const float4*)(c + i * 4);
        float acc = 0.f;
        #pragma unroll
        for (int i = 0; i < 16; ++i) acc += vv[i] * cc[i];
        #pragma unroll
        for (int off = 32; off > 0; off >>= 1) acc += __shfl_down(acc, off);
        if (lane == 0) s_buf[((size_t)(bc * F_) + f) * K_ + k] = acc;
    }
}

// ---------------------------------------------------------------------------
// 5. softmax over f per (bc,k)
__global__ void softmax_kernel(const float* __restrict__ s_buf,
                               float* __restrict__ attw) {
    int k = blockIdx.x, bc = blockIdx.y, tid = threadIdx.x;
    __shared__ float red[256];
    const float* sp = s_buf + (size_t)bc * F_ * K_ + k;
    float m = -INFINITY;
    for (int f = tid; f < F_; f += 256) m = fmaxf(m, sp[(size_t)f * K_]);
    red[tid] = m; __syncthreads();
    for (int s = 128; s > 0; s >>= 1) {
        if (tid < s) red[tid] = fmaxf(red[tid], red[tid + s]);
        __syncthreads();
    }
    m = red[0]; __syncthreads();
    float l = 0.f;
    for (int f = tid; f < F_; f += 256) l += __expf(sp[(size_t)f * K_] - m);
    red[tid] = l; __syncthreads();
    for (int s = 128; s > 0; s >>= 1) {
        if (tid < s) red[tid] += red[tid + s];
        __syncthreads();
    }
    l = red[0];
    float rl = 1.f / l;
    float* wp = attw + (size_t)bc * F_ * K_ + k;
    for (int f = tid; f < F_; f += 256) wp[(size_t)f * K_] = __expf(sp[(size_t)f * K_] - m) * rl;
}

// ---------------------------------------------------------------------------
// 6. o[k,d] = sum_f attw[bc,f,k] * v[bc,f,d]; bap[b,d] = sum_k o[k,d]*cls[b,k,d]
__global__ __launch_bounds__(128)
void o_bap_kernel(const __hip_bfloat16* __restrict__ v_buf,
                  const float* __restrict__ attw,
                  const float* __restrict__ cls_emb,
                  float* __restrict__ bap, int b0) {
    int tid = threadIdx.x;
    int dt = blockIdx.x;
    int bc = blockIdx.y;
    int d = dt * 128 + tid;
    int b = b0 + bc;
    __shared__ float wbuf[32 * K_];
    float acc[K_] = {};
    for (int fb = 0; fb < F_; fb += 32) {
        int nf = min(32, F_ - fb);
        for (int j = tid; j < nf * K_; j += 128)
            wbuf[j] = attw[((size_t)(bc * F_ + fb)) * K_ + j];
        __syncthreads();
        for (int ff = 0; ff < nf; ++ff) {
            float vv = (float)v_buf[((size_t)(bc * F_ + fb + ff)) * DT_ + d];
            #pragma unroll
            for (int k = 0; k < K_; ++k) acc[k] += wbuf[ff * K_ + k] * vv;
        }
        __syncthreads();
    }
    float bsum = 0.f;
    #pragma unroll
    for (int k = 0; k < K_; ++k)
        bsum += acc[k] * cls_emb[((size_t)b * K_ + k) * DT_ + d];
    bap[(size_t)b * DT_ + d] = bsum;
}

// ---------------------------------------------------------------------------
// 7. lg[b,k] = y[b,:] @ W_fc[:,k] + b_fc[k]; scatter into out
__global__ void final_kernel(const float* __restrict__ y,
                             const float* __restrict__ Wfc,
                             const float* __restrict__ bfc,
                             const int* __restrict__ topk_idx,
                             float* __restrict__ out) {
    int b = blockIdx.x, tid = threadIdx.x;
    int lane = tid & 63, wave = tid >> 6;
    float pk[K_] = {};
    for (int d = tid; d < DT_; d += 256) {
        float yv = y[(size_t)b * DT_ + d];
        #pragma unroll
        for (int k = 0; k < K_; ++k) pk[k] += yv * Wfc[(size_t)d * K_ + k];
    }
    __shared__ float wsum[4][K_];
    #pragma unroll
    for (int k = 0; k < K_; ++k) {
        float a = pk[k];
        #pragma unroll
        for (int off = 32; off > 0; off >>= 1) a += __shfl_down(a, off);
        if (lane == 0) wsum[wave][k] = a;
    }
    __syncthreads();
    if (tid < K_) {
        float lg = wsum[0][tid] + wsum[1][tid] + wsum[2][tid] + wsum[3][tid] + bfc[tid];
        out[(size_t)b * C_ + topk_idx[b * K_ + tid]] = lg;
    }
}

// ---------------------------------------------------------------------------
extern "C" void kernel_launch(void* const* d_in, const int* in_sizes, int n_in,
                              void* d_out, int out_size, void* d_ws, size_t ws_size,
                              hipStream_t stream) {
    const float* ftm           = (const float*)d_in[0];
    const float* logits        = (const float*)d_in[1];
    const int*   indices_table = (const int*)d_in[3];
    const float* word2vec      = (const float*)d_in[4];
    const float* W_emb         = (const float*)d_in[5];
    const float* b_emb         = (const float*)d_in[6];
    const float* W_cls         = (const float*)d_in[7];
    const float* b_cls         = (const float*)d_in[8];
    const float* W_v           = (const float*)d_in[9];
    const float* b_v           = (const float*)d_in[10];
    const float* W_bap         = (const float*)d_in[11];
    const float* b_bap         = (const float*)d_in[12];
    const float* W_fc          = (const float*)d_in[13];
    const float* b_fc          = (const float*)d_in[14];
    float* out = (float*)d_out;

    char* ws = (char*)d_ws;
    size_t off = 0;
    auto alloc = [&](size_t bytes) -> void* {
        void* p = ws + off;
        off = (off + bytes + 255) & ~(size_t)255;
        return p;
    };
    int*   topk_idx = (int*)  alloc((size_t)B_ * K_ * 4);
    float* emb      = (float*)alloc((size_t)B_ * K_ * DW_ * 4);
    float* cls1     = (float*)alloc((size_t)B_ * K_ * DT_ * 4);
    float* cls2     = (float*)alloc((size_t)B_ * K_ * DT_ * 4);
    __hip_bfloat16* W_t   = (__hip_bfloat16*)alloc((size_t)DT_ * DF_ * 2);
    __hip_bfloat16* ftm_t = (__hip_bfloat16*)alloc((size_t)CHUNK_B * F_ * DF_ * 2);
    __hip_bfloat16* v_buf = (__hip_bfloat16*)alloc((size_t)CHUNK_B * F_ * DT_ * 2);
    float* s_buf    = (float*)alloc((size_t)CHUNK_B * F_ * K_ * 4);
    float* attw     = (float*)alloc((size_t)CHUNK_B * F_ * K_ * 4);
    float* bap      = (float*)alloc((size_t)B_ * DT_ * 4);
    float* yb       = (float*)alloc((size_t)B_ * DT_ * 4);

    hipMemsetAsync(d_out, 0, (size_t)out_size * sizeof(float), stream);

    topk_kernel<<<B_, 256, 0, stream>>>(logits, topk_idx);
    emb_kernel<<<(B_ * K_ * DW_ + 255) / 256, 256, 0, stream>>>(
        topk_idx, indices_table, word2vec, emb);
    gemm_bias<1><<<dim3(B_ * K_ / 64, DT_ / 64), 256, 0, stream>>>(
        emb, W_emb, b_emb, cls1, B_ * K_, DT_, DW_);
    gemm_bias<1><<<dim3(B_ * K_ / 64, DT_ / 64), 256, 0, stream>>>(
        cls1, W_cls, b_cls, cls2, B_ * K_, DT_, DT_);

    // W_v [768][1024] -> W_t [1024][768] bf16, once
    transpose_cvt<<<dim3(DT_ / 64, DF_ / 64, 1), 256, 0, stream>>>(
        W_v, W_t, DF_, DT_, 0, 0);

    for (int c = 0; c < N_CHUNKS; ++c) {
        int b0 = c * CHUNK_B;
        // ftm[b][kd][f] -> ftm_t[bc][f][kd] bf16
        transpose_cvt<<<dim3((F_ + 63) / 64, DF_ / 64, CHUNK_B), 256, 0, stream>>>(
            ftm + (size_t)b0 * DF_ * F_, ftm_t, DF_, F_,
            (size_t)DF_ * F_, (size_t)F_ * DF_);
        gemm_v_mfma<<<dim3((F_ + 127) / 128, DT_ / 128, CHUNK_B), 256, 0, stream>>>(
            ftm_t, W_t, b_v, v_buf);
        attn_s_kernel<<<dim3(F_ / 4, CHUNK_B), 256, 0, stream>>>(
            v_buf, cls2, s_buf, b0);
        softmax_kernel<<<dim3(K_, CHUNK_B), 256, 0, stream>>>(s_buf, attw);
        o_bap_kernel<<<dim3(DT_ / 128, CHUNK_B), 128, 0, stream>>>(
            v_buf, attw, cls2, bap, b0);
    }

    gemm_bias<1><<<dim3(B_ / 64, DT_ / 64), 256, 0, stream>>>(
        bap, W_bap, b_bap, yb, B_, DT_, DT_);
    final_kernel<<<B_, 256, 0, stream>>>(yb, W_fc, b_fc, topk_idx, out);
}

// Round 3
// 629.386 us; speedup vs baseline: 3.6174x; 2.3659x over previous
//
#include <hip/hip_runtime.h>
#include <hip/hip_bf16.h>

// Problem constants
#define B_   64
#define C_   3129
#define K_   10
#define DF_  768
#define F_   676      // 26*26
#define DW_  300
#define DWP_ 320      // DW_ padded to multiple of 32 (MFMA K-tile)
#define DT_  1024

typedef __attribute__((ext_vector_type(8))) short short8;   // 8 bf16
typedef __attribute__((ext_vector_type(4))) float floatx4;  // 4 fp32

// ---------------------------------------------------------------------------
// 1. top-k (K=10) per row of logits [B, C], exact lax.top_k order.
__global__ void topk_kernel(const float* __restrict__ logits,
                            int* __restrict__ topk_idx) {
    __shared__ float vals[C_];
    __shared__ float red_v[256];
    __shared__ int   red_i[256];
    int b = blockIdx.x;
    int tid = threadIdx.x;
    for (int i = tid; i < C_; i += 256) vals[i] = logits[(size_t)b * C_ + i];
    __syncthreads();
    for (int sel = 0; sel < K_; ++sel) {
        float bv = -INFINITY; int bi = 0x7fffffff;
        for (int i = tid; i < C_; i += 256) {
            float v = vals[i];
            if (v > bv) { bv = v; bi = i; }
        }
        red_v[tid] = bv; red_i[tid] = bi;
        __syncthreads();
        for (int s = 128; s > 0; s >>= 1) {
            if (tid < s) {
                float ov = red_v[tid + s]; int oi = red_i[tid + s];
                if (ov > red_v[tid] || (ov == red_v[tid] && oi < red_i[tid])) {
                    red_v[tid] = ov; red_i[tid] = oi;
                }
            }
            __syncthreads();
        }
        if (tid == 0) {
            topk_idx[b * K_ + sel] = red_i[0];
            vals[red_i[0]] = -INFINITY;
        }
        __syncthreads();
    }
}

// ---------------------------------------------------------------------------
// 2. emb[bk][j] (bf16, K-padded to DWP_ with zeros)
__global__ void emb_kernel(const int* __restrict__ topk_idx,
                           const int* __restrict__ indices_table,
                           const float* __restrict__ word2vec,
                           __hip_bfloat16* __restrict__ emb) {
    int idx = blockIdx.x * blockDim.x + threadIdx.x;
    if (idx >= B_ * K_ * DWP_) return;
    int j  = idx % DWP_;
    int bk = idx / DWP_;
    float s = 0.f;
    if (j < DW_) {
        int cls = topk_idx[bk];
        const int* tbl = indices_table + (size_t)cls * 4;
        #pragma unroll
        for (int i = 0; i < 4; ++i) s += word2vec[(size_t)tbl[i] * DW_ + j];
        s *= 0.25f;
    }
    emb[idx] = (__hip_bfloat16)s;
}

// ---------------------------------------------------------------------------
// Transpose + fp32->bf16 + zero-pad: src[R][Cc] fp32 -> dst[Cc][Rp] bf16.
// dst[c][r] = (r < R) ? src[r][c] : 0.  Rp % 64 == 0, Cc % 4 == 0.
// grid: (ceil(Cc/64), Rp/64, nbatch); strides in elements.
__global__ __launch_bounds__(256)
void transpose_pad_cvt(const float* __restrict__ src,
                       __hip_bfloat16* __restrict__ dst,
                       int R, int Cc, int Rp, size_t sbs, size_t dbs) {
    __shared__ float tile[64][65];
    const float* s = src + (size_t)blockIdx.z * sbs;
    __hip_bfloat16* d = dst + (size_t)blockIdx.z * dbs;
    int c0 = blockIdx.x * 64;
    int r0 = blockIdx.y * 64;
    int t = threadIdx.x;
    int cl = (t & 15) * 4;
    int rl = t >> 4;
    #pragma unroll
    for (int i = 0; i < 4; ++i) {
        int r = rl + i * 16;
        float4 v = make_float4(0.f, 0.f, 0.f, 0.f);
        if (r0 + r < R && c0 + cl < Cc)
            v = *(const float4*)(s + (size_t)(r0 + r) * Cc + c0 + cl);
        tile[r][cl + 0] = v.x; tile[r][cl + 1] = v.y;
        tile[r][cl + 2] = v.z; tile[r][cl + 3] = v.w;
    }
    __syncthreads();
    int cw = t >> 2;            // dst row (source column)
    int r4 = (t & 3) * 16;      // dst col offset
    if (c0 + cw < Cc) {
        __align__(16) __hip_bfloat16 buf[16];
        #pragma unroll
        for (int j = 0; j < 16; ++j) buf[j] = (__hip_bfloat16)tile[r4 + j][cw];
        float4* dp = (float4*)(d + (size_t)(c0 + cw) * Rp + r0 + r4);
        dp[0] = *(float4*)&buf[0];
        dp[1] = *(float4*)&buf[8];
    }
}

// ---------------------------------------------------------------------------
// Shared MFMA bf16 GEMM: C[M][N] = act(A[M][Kp] @ Bt[N][Kp]^T + bias)
// 128x128 tile, BK=32, 2x2 waves x 4x4 16x16x32 frags. M ragged (guarded),
// N % 128 == 0, Kp % 32 == 0.
#define PAD_K 40    // 80 B row stride: 16B-aligned, 2-way-max bank aliasing
template <int RELU, int OUTBF>
__global__ __launch_bounds__(256)
void gemm_mfma(const __hip_bfloat16* __restrict__ A,
               const __hip_bfloat16* __restrict__ Bt,
               const float* __restrict__ bias,
               void* __restrict__ Cout, int M, int N, int Kp) {
    __shared__ __align__(16) __hip_bfloat16 As[128 * PAD_K];
    __shared__ __align__(16) __hip_bfloat16 Bs[128 * PAD_K];
    int tid = threadIdx.x;
    int wave = tid >> 6, lane = tid & 63;
    int quad = lane >> 4, l16 = lane & 15;
    int wm = (wave & 1) * 64, wn = (wave >> 1) * 64;
    int m0 = blockIdx.x * 128;
    int n0 = blockIdx.y * 128;

    floatx4 acc[4][4];
    #pragma unroll
    for (int i = 0; i < 4; ++i)
        #pragma unroll
        for (int j = 0; j < 4; ++j)
            acc[i][j] = (floatx4){0.f, 0.f, 0.f, 0.f};

    int row_a0 = tid >> 2, half = tid & 3;

    for (int k0 = 0; k0 < Kp; k0 += 32) {
        #pragma unroll
        for (int i = 0; i < 2; ++i) {
            int row = row_a0 + i * 64;
            int r = m0 + row;
            float4 a4 = make_float4(0.f, 0.f, 0.f, 0.f);
            if (r < M)
                a4 = *(const float4*)(A + (size_t)r * Kp + k0 + half * 8);
            *(float4*)&As[row * PAD_K + half * 8] = a4;
            int n = n0 + row;
            float4 b4 = *(const float4*)(Bt + (size_t)n * Kp + k0 + half * 8);
            *(float4*)&Bs[row * PAD_K + half * 8] = b4;
        }
        __syncthreads();
        short8 af[4], bf[4];
        #pragma unroll
        for (int mi = 0; mi < 4; ++mi)
            af[mi] = *(const short8*)&As[(wm + mi * 16 + l16) * PAD_K + quad * 8];
        #pragma unroll
        for (int ni = 0; ni < 4; ++ni)
            bf[ni] = *(const short8*)&Bs[(wn + ni * 16 + l16) * PAD_K + quad * 8];
        #pragma unroll
        for (int mi = 0; mi < 4; ++mi)
            #pragma unroll
            for (int ni = 0; ni < 4; ++ni)
                acc[mi][ni] = __builtin_amdgcn_mfma_f32_16x16x32_bf16(
                    af[mi], bf[ni], acc[mi][ni], 0, 0, 0);
        __syncthreads();
    }

    // C/D mapping: col = lane&15, row = quad*4 + reg  [measured m89/m91]
    float bn[4];
    #pragma unroll
    for (int ni = 0; ni < 4; ++ni) bn[ni] = bias[n0 + wn + ni * 16 + l16];
    #pragma unroll
    for (int mi = 0; mi < 4; ++mi) {
        #pragma unroll
        for (int rr = 0; rr < 4; ++rr) {
            int r = m0 + wm + mi * 16 + quad * 4 + rr;
            if (r < M) {
                size_t base = (size_t)r * N;
                #pragma unroll
                for (int ni = 0; ni < 4; ++ni) {
                    int n = n0 + wn + ni * 16 + l16;
                    float val = acc[mi][ni][rr] + bn[ni];
                    if (RELU) val = fmaxf(val, 0.f);
                    if (OUTBF)
                        ((__hip_bfloat16*)Cout)[base + n] = (__hip_bfloat16)val;
                    else
                        ((float*)Cout)[base + n] = val;
                }
            }
        }
    }
}

// ---------------------------------------------------------------------------
// 4. s[bc,f,k] = sum_d v[bc,f,d] * cls[b0+bc,k,d]   (v, cls bf16)
__global__ __launch_bounds__(256)
void attn_s_kernel(const __hip_bfloat16* __restrict__ v_buf,
                   const __hip_bfloat16* __restrict__ cls,
                   float* __restrict__ s_buf, int b0) {
    int tid = threadIdx.x;
    int wave = tid >> 6, lane = tid & 63;
    int bc = blockIdx.y;
    int f = blockIdx.x * 4 + wave;   // 169*4 == 676
    union U { float4 f4; __hip_bfloat16 h[8]; };
    const float4* vp = (const float4*)(v_buf + ((size_t)(bc * F_ + f)) * DT_ + lane * 16);
    U u0, u1; u0.f4 = vp[0]; u1.f4 = vp[1];
    float vv[16];
    #pragma unroll
    for (int i = 0; i < 8; ++i) { vv[i] = (float)u0.h[i]; vv[8 + i] = (float)u1.h[i]; }
    const __hip_bfloat16* cp = cls + ((size_t)(b0 + bc) * K_) * DT_ + lane * 16;
    #pragma unroll
    for (int k = 0; k < K_; ++k) {
        const float4* c4 = (const float4*)(cp + (size_t)k * DT_);
        U c0u, c1u; c0u.f4 = c4[0]; c1u.f4 = c4[1];
        float acc = 0.f;
        #pragma unroll
        for (int i = 0; i < 8; ++i)
            acc += vv[i] * (float)c0u.h[i] + vv[8 + i] * (float)c1u.h[i];
        #pragma unroll
        for (int off = 32; off > 0; off >>= 1) acc += __shfl_down(acc, off);
        if (lane == 0) s_buf[((size_t)(bc * F_) + f) * K_ + k] = acc;
    }
}

// ---------------------------------------------------------------------------
// 5. softmax over f per (bc,k)
__global__ void softmax_kernel(const float* __restrict__ s_buf,
                               float* __restrict__ attw) {
    int k = blockIdx.x, bc = blockIdx.y, tid = threadIdx.x;
    __shared__ float red[256];
    const float* sp = s_buf + (size_t)bc * F_ * K_ + k;
    float m = -INFINITY;
    for (int f = tid; f < F_; f += 256) m = fmaxf(m, sp[(size_t)f * K_]);
    red[tid] = m; __syncthreads();
    for (int s = 128; s > 0; s >>= 1) {
        if (tid < s) red[tid] = fmaxf(red[tid], red[tid + s]);
        __syncthreads();
    }
    m = red[0]; __syncthreads();
    float l = 0.f;
    for (int f = tid; f < F_; f += 256) l += __expf(sp[(size_t)f * K_] - m);
    red[tid] = l; __syncthreads();
    for (int s = 128; s > 0; s >>= 1) {
        if (tid < s) red[tid] += red[tid + s];
        __syncthreads();
    }
    l = red[0];
    float rl = 1.f / l;
    float* wp = attw + (size_t)bc * F_ * K_ + k;
    for (int f = tid; f < F_; f += 256) wp[(size_t)f * K_] = __expf(sp[(size_t)f * K_] - m) * rl;
}

// ---------------------------------------------------------------------------
// 6. bap[b0+bc,d] = sum_k (sum_f attw[bc,f,k]*v[bc,f,d]) * cls[b0+bc,k,d]
__global__ __launch_bounds__(128)
void o_bap_kernel(const __hip_bfloat16* __restrict__ v_buf,
                  const float* __restrict__ attw,
                  const __hip_bfloat16* __restrict__ cls,
                  __hip_bfloat16* __restrict__ bap, int b0) {
    int tid = threadIdx.x;
    int dt = blockIdx.x;
    int bc = blockIdx.y;
    int d = dt * 128 + tid;
    int b = b0 + bc;
    __shared__ float wbuf[32 * K_];
    float acc[K_] = {};
    for (int fb = 0; fb < F_; fb += 32) {
        int nf = min(32, F_ - fb);
        for (int j = tid; j < nf * K_; j += 128)
            wbuf[j] = attw[((size_t)(bc * F_ + fb)) * K_ + j];
        __syncthreads();
        for (int ff = 0; ff < nf; ++ff) {
            float vv = (float)v_buf[((size_t)(bc * F_ + fb + ff)) * DT_ + d];
            #pragma unroll
            for (int k = 0; k < K_; ++k) acc[k] += wbuf[ff * K_ + k] * vv;
        }
        __syncthreads();
    }
    float bsum = 0.f;
    #pragma unroll
    for (int k = 0; k < K_; ++k)
        bsum += acc[k] * (float)cls[((size_t)b * K_ + k) * DT_ + d];
    bap[(size_t)b * DT_ + d] = (__hip_bfloat16)bsum;
}

// ---------------------------------------------------------------------------
// 7. lg[b,k] = y[b,:] @ W_fc[:,k] + b_fc[k]; scatter into out
__global__ void final_kernel(const float* __restrict__ y,
                             const float* __restrict__ Wfc,
                             const float* __restrict__ bfc,
                             const int* __restrict__ topk_idx,
                             float* __restrict__ out) {
    int b = blockIdx.x, tid = threadIdx.x;
    int lane = tid & 63, wave = tid >> 6;
    float pk[K_] = {};
    for (int d = tid; d < DT_; d += 256) {
        float yv = y[(size_t)b * DT_ + d];
        #pragma unroll
        for (int k = 0; k < K_; ++k) pk[k] += yv * Wfc[(size_t)d * K_ + k];
    }
    __shared__ float wsum[4][K_];
    #pragma unroll
    for (int k = 0; k < K_; ++k) {
        float a = pk[k];
        #pragma unroll
        for (int off = 32; off > 0; off >>= 1) a += __shfl_down(a, off);
        if (lane == 0) wsum[wave][k] = a;
    }
    __syncthreads();
    if (tid < K_) {
        float lg = wsum[0][tid] + wsum[1][tid] + wsum[2][tid] + wsum[3][tid] + bfc[tid];
        out[(size_t)b * C_ + topk_idx[b * K_ + tid]] = lg;
    }
}

// ---------------------------------------------------------------------------
extern "C" void kernel_launch(void* const* d_in, const int* in_sizes, int n_in,
                              void* d_out, int out_size, void* d_ws, size_t ws_size,
                              hipStream_t stream) {
    const float* ftm           = (const float*)d_in[0];
    const float* logits        = (const float*)d_in[1];
    const int*   indices_table = (const int*)d_in[3];
    const float* word2vec      = (const float*)d_in[4];
    const float* W_emb         = (const float*)d_in[5];
    const float* b_emb         = (const float*)d_in[6];
    const float* W_cls         = (const float*)d_in[7];
    const float* b_cls         = (const float*)d_in[8];
    const float* W_v           = (const float*)d_in[9];
    const float* b_v           = (const float*)d_in[10];
    const float* W_bap         = (const float*)d_in[11];
    const float* b_bap         = (const float*)d_in[12];
    const float* W_fc          = (const float*)d_in[13];
    const float* b_fc          = (const float*)d_in[14];
    float* out = (float*)d_out;

    char* ws = (char*)d_ws;
    size_t off = 0;
    auto alloc = [&](size_t bytes) -> void* {
        void* p = ws + off;
        off = (off + bytes + 255) & ~(size_t)255;
        return p;
    };
    int*            topk_idx = (int*)           alloc((size_t)B_ * K_ * 4);
    __hip_bfloat16* emb_bf   = (__hip_bfloat16*)alloc((size_t)B_ * K_ * DWP_ * 2);
    __hip_bfloat16* cls1     = (__hip_bfloat16*)alloc((size_t)B_ * K_ * DT_ * 2);
    __hip_bfloat16* cls2     = (__hip_bfloat16*)alloc((size_t)B_ * K_ * DT_ * 2);
    __hip_bfloat16* Wemb_t   = (__hip_bfloat16*)alloc((size_t)DT_ * DWP_ * 2);
    __hip_bfloat16* Wcls_t   = (__hip_bfloat16*)alloc((size_t)DT_ * DT_ * 2);
    __hip_bfloat16* Wv_t     = (__hip_bfloat16*)alloc((size_t)DT_ * DF_ * 2);
    __hip_bfloat16* Wbap_t   = (__hip_bfloat16*)alloc((size_t)DT_ * DT_ * 2);
    float*          s_buf    = (float*)         alloc((size_t)B_ * F_ * K_ * 4);
    float*          attw     = (float*)         alloc((size_t)B_ * F_ * K_ * 4);
    __hip_bfloat16* bap_bf   = (__hip_bfloat16*)alloc((size_t)B_ * DT_ * 2);
    float*          yb       = (float*)         alloc((size_t)B_ * DT_ * 4);

    // dynamic batch-chunk: fit ftm_t + v for nb batches in remaining ws
    size_t per_b = (size_t)F_ * DF_ * 2 + (size_t)F_ * DT_ * 2;
    size_t avail = (ws_size > off + 8192) ? ws_size - off - 8192 : 0;
    int nb = (int)(avail / per_b);
    if (nb > B_) nb = B_;
    if (nb < 1) nb = 1;
    __hip_bfloat16* ftm_t = (__hip_bfloat16*)alloc((size_t)nb * F_ * DF_ * 2);
    __hip_bfloat16* v_buf = (__hip_bfloat16*)alloc((size_t)nb * F_ * DT_ * 2);

    hipMemsetAsync(d_out, 0, (size_t)out_size * sizeof(float), stream);

    topk_kernel<<<B_, 256, 0, stream>>>(logits, topk_idx);
    emb_kernel<<<(B_ * K_ * DWP_ + 255) / 256, 256, 0, stream>>>(
        topk_idx, indices_table, word2vec, emb_bf);

    // weight transposes (fp32 [K][N] -> bf16 [N][Kp])
    transpose_pad_cvt<<<dim3(DT_ / 64, DWP_ / 64, 1), 256, 0, stream>>>(
        W_emb, Wemb_t, DW_, DT_, DWP_, 0, 0);
    transpose_pad_cvt<<<dim3(DT_ / 64, DT_ / 64, 1), 256, 0, stream>>>(
        W_cls, Wcls_t, DT_, DT_, DT_, 0, 0);
    transpose_pad_cvt<<<dim3(DT_ / 64, DF_ / 64, 1), 256, 0, stream>>>(
        W_v, Wv_t, DF_, DT_, DF_, 0, 0);
    transpose_pad_cvt<<<dim3(DT_ / 64, DT_ / 64, 1), 256, 0, stream>>>(
        W_bap, Wbap_t, DT_, DT_, DT_, 0, 0);

    // cls path (MFMA)
    gemm_mfma<1, 1><<<dim3((B_ * K_ + 127) / 128, DT_ / 128), 256, 0, stream>>>(
        emb_bf, Wemb_t, b_emb, cls1, B_ * K_, DT_, DWP_);
    gemm_mfma<1, 1><<<dim3((B_ * K_ + 127) / 128, DT_ / 128), 256, 0, stream>>>(
        cls1, Wcls_t, b_cls, cls2, B_ * K_, DT_, DT_);

    // main path, chunked only if ws is small (nb == 64 -> single pass)
    for (int b0 = 0; b0 < B_; b0 += nb) {
        int cb = min(nb, B_ - b0);
        transpose_pad_cvt<<<dim3((F_ + 63) / 64, DF_ / 64, cb), 256, 0, stream>>>(
            ftm + (size_t)b0 * DF_ * F_, ftm_t, DF_, F_, DF_,
            (size_t)DF_ * F_, (size_t)F_ * DF_);
        int M = cb * F_;
        gemm_mfma<1, 1><<<dim3((M + 127) / 128, DT_ / 128), 256, 0, stream>>>(
            ftm_t, Wv_t, b_v, v_buf, M, DT_, DF_);
        float* s_c = s_buf + (size_t)b0 * F_ * K_;
        float* w_c = attw  + (size_t)b0 * F_ * K_;
        attn_s_kernel<<<dim3(F_ / 4, cb), 256, 0, stream>>>(
            v_buf, cls2, s_c, b0);
        softmax_kernel<<<dim3(K_, cb), 256, 0, stream>>>(s_c, w_c);
        o_bap_kernel<<<dim3(DT_ / 128, cb), 128, 0, stream>>>(
            v_buf, w_c, cls2, bap_bf, b0);
    }

    gemm_mfma<1, 0><<<dim3(1, DT_ / 128), 256, 0, stream>>>(
        bap_bf, Wbap_t, b_bap, yb, B_, DT_, DT_);
    final_kernel<<<B_, 256, 0, stream>>>(yb, W_fc, b_fc, topk_idx, out);
}

// Round 4
// 588.063 us; speedup vs baseline: 3.8716x; 1.0703x over previous
//
#include <hip/hip_runtime.h>
#include <hip/hip_bf16.h>

// Problem constants
#define B_   64
#define C_   3129
#define K_   10
#define DF_  768
#define F_   676      // 26*26
#define DW_  300
#define DWP_ 320      // DW_ padded to multiple of 32 (MFMA K-tile)
#define DT_  1024
#define NSEG 4        // o_bap f-segments: 676 = 4*169
#define FSEG 169

typedef __attribute__((ext_vector_type(8))) short short8;   // 8 bf16
typedef __attribute__((ext_vector_type(4))) float floatx4;  // 4 fp32

// async 16B global -> LDS (wave-uniform LDS base + lane*16)
__device__ __forceinline__ void gload_lds16(const void* g, void* l) {
    __builtin_amdgcn_global_load_lds(
        (const __attribute__((address_space(1))) void*)g,
        (__attribute__((address_space(3))) void*)l, 16, 0, 0);
}

// ---------------------------------------------------------------------------
// 1. top-k (K=10) per row of logits [B, C], exact lax.top_k order.
__global__ void topk_kernel(const float* __restrict__ logits,
                            int* __restrict__ topk_idx) {
    __shared__ float vals[C_];
    __shared__ float red_v[256];
    __shared__ int   red_i[256];
    int b = blockIdx.x;
    int tid = threadIdx.x;
    for (int i = tid; i < C_; i += 256) vals[i] = logits[(size_t)b * C_ + i];
    __syncthreads();
    for (int sel = 0; sel < K_; ++sel) {
        float bv = -INFINITY; int bi = 0x7fffffff;
        for (int i = tid; i < C_; i += 256) {
            float v = vals[i];
            if (v > bv) { bv = v; bi = i; }
        }
        red_v[tid] = bv; red_i[tid] = bi;
        __syncthreads();
        for (int s = 128; s > 0; s >>= 1) {
            if (tid < s) {
                float ov = red_v[tid + s]; int oi = red_i[tid + s];
                if (ov > red_v[tid] || (ov == red_v[tid] && oi < red_i[tid])) {
                    red_v[tid] = ov; red_i[tid] = oi;
                }
            }
            __syncthreads();
        }
        if (tid == 0) {
            topk_idx[b * K_ + sel] = red_i[0];
            vals[red_i[0]] = -INFINITY;
        }
        __syncthreads();
    }
}

// ---------------------------------------------------------------------------
// 2. emb[bk][j] (bf16, K-padded to DWP_ with zeros)
__global__ void emb_kernel(const int* __restrict__ topk_idx,
                           const int* __restrict__ indices_table,
                           const float* __restrict__ word2vec,
                           __hip_bfloat16* __restrict__ emb) {
    int idx = blockIdx.x * blockDim.x + threadIdx.x;
    if (idx >= B_ * K_ * DWP_) return;
    int j  = idx % DWP_;
    int bk = idx / DWP_;
    float s = 0.f;
    if (j < DW_) {
        int cls = topk_idx[bk];
        const int* tbl = indices_table + (size_t)cls * 4;
        #pragma unroll
        for (int i = 0; i < 4; ++i) s += word2vec[(size_t)tbl[i] * DW_ + j];
        s *= 0.25f;
    }
    emb[idx] = (__hip_bfloat16)s;
}

// ---------------------------------------------------------------------------
// Transpose + fp32->bf16 + zero-pad: src[R][Cc] fp32 -> dst[Cc][Rp] bf16.
__global__ __launch_bounds__(256)
void transpose_pad_cvt(const float* __restrict__ src,
                       __hip_bfloat16* __restrict__ dst,
                       int R, int Cc, int Rp, size_t sbs, size_t dbs) {
    __shared__ float tile[64][65];
    const float* s = src + (size_t)blockIdx.z * sbs;
    __hip_bfloat16* d = dst + (size_t)blockIdx.z * dbs;
    int c0 = blockIdx.x * 64;
    int r0 = blockIdx.y * 64;
    int t = threadIdx.x;
    int cl = (t & 15) * 4;
    int rl = t >> 4;
    #pragma unroll
    for (int i = 0; i < 4; ++i) {
        int r = rl + i * 16;
        float4 v = make_float4(0.f, 0.f, 0.f, 0.f);
        if (r0 + r < R && c0 + cl < Cc)
            v = *(const float4*)(s + (size_t)(r0 + r) * Cc + c0 + cl);
        tile[r][cl + 0] = v.x; tile[r][cl + 1] = v.y;
        tile[r][cl + 2] = v.z; tile[r][cl + 3] = v.w;
    }
    __syncthreads();
    int cw = t >> 2;
    int r4 = (t & 3) * 16;
    if (c0 + cw < Cc) {
        __align__(16) __hip_bfloat16 buf[16];
        #pragma unroll
        for (int j = 0; j < 16; ++j) buf[j] = (__hip_bfloat16)tile[r4 + j][cw];
        float4* dp = (float4*)(d + (size_t)(c0 + cw) * Rp + r0 + r4);
        dp[0] = *(float4*)&buf[0];
        dp[1] = *(float4*)&buf[8];
    }
}

// ---------------------------------------------------------------------------
// MFMA bf16 GEMM, m97-style staging: C[M][N] = act(A[M][Kp] @ Bt[N][Kp]^T + b)
// 128x128 tile, BK=32, global_load_lds width-16 into unpadded LDS [128][32].
// M ragged (A row index clamped; stores guarded). N % 128 == 0, Kp % 32 == 0.
template <int RELU, int OUTBF>
__global__ __launch_bounds__(256)
void gemm_mfma(const __hip_bfloat16* __restrict__ A,
               const __hip_bfloat16* __restrict__ Bt,
               const float* __restrict__ bias,
               void* __restrict__ Cout, int M, int N, int Kp) {
    __shared__ __align__(16) __hip_bfloat16 As[128 * 32];
    __shared__ __align__(16) __hip_bfloat16 Bs[128 * 32];
    int tid = threadIdx.x;
    int wave = tid >> 6, lane = tid & 63;
    int quad = lane >> 4, l16 = lane & 15;
    int wm = (wave & 1) * 64, wn = (wave >> 1) * 64;
    int m0 = blockIdx.x * 128;
    int n0 = blockIdx.y * 128;

    floatx4 acc[4][4];
    #pragma unroll
    for (int i = 0; i < 4; ++i)
        #pragma unroll
        for (int j = 0; j < 4; ++j)
            acc[i][j] = (floatx4){0.f, 0.f, 0.f, 0.f};

    // staging: wave w, call c covers LDS rows [(w*2+c)*16, +16), 64B/row.
    // lane l -> row sub l>>2, 16B part l&3.  LDS base is wave-uniform.
    int rsub = lane >> 2, part = lane & 3;

    for (int k0 = 0; k0 < Kp; k0 += 32) {
        #pragma unroll
        for (int c = 0; c < 2; ++c) {
            int rowblk = (wave * 2 + c) * 16;
            int row = rowblk + rsub;
            int ra = m0 + row; if (ra >= M) ra = M - 1;   // clamp: junk rows unused
            gload_lds16(A + (size_t)ra * Kp + k0 + part * 8,
                        &As[rowblk * 32]);
            gload_lds16(Bt + (size_t)(n0 + row) * Kp + k0 + part * 8,
                        &Bs[rowblk * 32]);
        }
        __syncthreads();
        short8 af[4], bf[4];
        #pragma unroll
        for (int mi = 0; mi < 4; ++mi)
            af[mi] = *(const short8*)&As[(wm + mi * 16 + l16) * 32 + quad * 8];
        #pragma unroll
        for (int ni = 0; ni < 4; ++ni)
            bf[ni] = *(const short8*)&Bs[(wn + ni * 16 + l16) * 32 + quad * 8];
        #pragma unroll
        for (int mi = 0; mi < 4; ++mi)
            #pragma unroll
            for (int ni = 0; ni < 4; ++ni)
                acc[mi][ni] = __builtin_amdgcn_mfma_f32_16x16x32_bf16(
                    af[mi], bf[ni], acc[mi][ni], 0, 0, 0);
        __syncthreads();
    }

    // C/D mapping: col = lane&15, row = quad*4 + reg  [measured m89/m91]
    float bn[4];
    #pragma unroll
    for (int ni = 0; ni < 4; ++ni) bn[ni] = bias[n0 + wn + ni * 16 + l16];
    #pragma unroll
    for (int mi = 0; mi < 4; ++mi) {
        #pragma unroll
        for (int rr = 0; rr < 4; ++rr) {
            int r = m0 + wm + mi * 16 + quad * 4 + rr;
            if (r < M) {
                size_t base = (size_t)r * N;
                #pragma unroll
                for (int ni = 0; ni < 4; ++ni) {
                    int n = n0 + wn + ni * 16 + l16;
                    float val = acc[mi][ni][rr] + bn[ni];
                    if (RELU) val = fmaxf(val, 0.f);
                    if (OUTBF)
                        ((__hip_bfloat16*)Cout)[base + n] = (__hip_bfloat16)val;
                    else
                        ((float*)Cout)[base + n] = val;
                }
            }
        }
    }
}

// ---------------------------------------------------------------------------
// 4. s[bc,f,k] = sum_d v[bc,f,d] * cls[b0+bc,k,d]   (v, cls bf16)
__global__ __launch_bounds__(256)
void attn_s_kernel(const __hip_bfloat16* __restrict__ v_buf,
                   const __hip_bfloat16* __restrict__ cls,
                   float* __restrict__ s_buf, int b0) {
    int tid = threadIdx.x;
    int wave = tid >> 6, lane = tid & 63;
    int bc = blockIdx.y;
    int f = blockIdx.x * 4 + wave;   // 169*4 == 676
    union U { float4 f4; __hip_bfloat16 h[8]; };
    const float4* vp = (const float4*)(v_buf + ((size_t)(bc * F_ + f)) * DT_ + lane * 16);
    U u0, u1; u0.f4 = vp[0]; u1.f4 = vp[1];
    float vv[16];
    #pragma unroll
    for (int i = 0; i < 8; ++i) { vv[i] = (float)u0.h[i]; vv[8 + i] = (float)u1.h[i]; }
    const __hip_bfloat16* cp = cls + ((size_t)(b0 + bc) * K_) * DT_ + lane * 16;
    #pragma unroll
    for (int k = 0; k < K_; ++k) {
        const float4* c4 = (const float4*)(cp + (size_t)k * DT_);
        U c0u, c1u; c0u.f4 = c4[0]; c1u.f4 = c4[1];
        float acc = 0.f;
        #pragma unroll
        for (int i = 0; i < 8; ++i)
            acc += vv[i] * (float)c0u.h[i] + vv[8 + i] * (float)c1u.h[i];
        #pragma unroll
        for (int off = 32; off > 0; off >>= 1) acc += __shfl_down(acc, off);
        if (lane == 0) s_buf[((size_t)(bc * F_) + f) * K_ + k] = acc;
    }
}

// ---------------------------------------------------------------------------
// 5. softmax over f per (bc,k)
__global__ void softmax_kernel(const float* __restrict__ s_buf,
                               float* __restrict__ attw) {
    int k = blockIdx.x, bc = blockIdx.y, tid = threadIdx.x;
    __shared__ float red[256];
    const float* sp = s_buf + (size_t)bc * F_ * K_ + k;
    float m = -INFINITY;
    for (int f = tid; f < F_; f += 256) m = fmaxf(m, sp[(size_t)f * K_]);
    red[tid] = m; __syncthreads();
    for (int s = 128; s > 0; s >>= 1) {
        if (tid < s) red[tid] = fmaxf(red[tid], red[tid + s]);
        __syncthreads();
    }
    m = red[0]; __syncthreads();
    float l = 0.f;
    for (int f = tid; f < F_; f += 256) l += __expf(sp[(size_t)f * K_] - m);
    red[tid] = l; __syncthreads();
    for (int s = 128; s > 0; s >>= 1) {
        if (tid < s) red[tid] += red[tid + s];
        __syncthreads();
    }
    l = red[0];
    float rl = 1.f / l;
    float* wp = attw + (size_t)bc * F_ * K_ + k;
    for (int f = tid; f < F_; f += 256) wp[(size_t)f * K_] = __expf(sp[(size_t)f * K_] - m) * rl;
}

// ---------------------------------------------------------------------------
// 6a. partial bap over f-segment (cls-dot applied; it's linear in the f-sum):
//     pp[seg][b][d] = sum_k cls[b,k,d] * sum_{f in seg} attw[bc,f,k]*v[bc,f,d]
__global__ __launch_bounds__(256)
void o_bap_partial(const __hip_bfloat16* __restrict__ v_buf,
                   const float* __restrict__ attw,
                   const __hip_bfloat16* __restrict__ cls,
                   float* __restrict__ pp, int b0) {
    int bc = blockIdx.x, seg = blockIdx.y;
    int b = b0 + bc;
    int t = threadIdx.x;
    int f0 = seg * FSEG;
    __shared__ float wbuf[FSEG * K_];
    for (int j = t; j < FSEG * K_; j += 256)
        wbuf[j] = attw[((size_t)bc * F_ + f0) * K_ + j];
    __syncthreads();
    int d0 = t * 4;
    float acc[K_][4] = {};
    const __hip_bfloat16* vp = v_buf + ((size_t)bc * F_ + f0) * DT_ + d0;
    for (int f = 0; f < FSEG; ++f) {
        union { float2 f2; __hip_bfloat16 h[4]; } u;
        u.f2 = *(const float2*)(vp + (size_t)f * DT_);
        float vv[4];
        #pragma unroll
        for (int i = 0; i < 4; ++i) vv[i] = (float)u.h[i];
        const float* wk = &wbuf[f * K_];
        #pragma unroll
        for (int k = 0; k < K_; ++k)
            #pragma unroll
            for (int i = 0; i < 4; ++i) acc[k][i] += wk[k] * vv[i];
    }
    union { float2 f2; __hip_bfloat16 h[4]; } cu;
    float outv[4] = {};
    #pragma unroll
    for (int k = 0; k < K_; ++k) {
        cu.f2 = *(const float2*)(cls + ((size_t)b * K_ + k) * DT_ + d0);
        #pragma unroll
        for (int i = 0; i < 4; ++i) outv[i] += acc[k][i] * (float)cu.h[i];
    }
    float* pd = pp + ((size_t)seg * B_ + b) * DT_ + d0;
    *(float4*)pd = *(float4*)outv;
}

// 6b. combine segments -> bf16 bap
__global__ void bap_combine(const float* __restrict__ pp,
                            __hip_bfloat16* __restrict__ bap) {
    int idx = blockIdx.x * 256 + threadIdx.x;   // B_*DT_ total
    float s = pp[idx] + pp[idx + B_ * DT_] + pp[idx + 2 * B_ * DT_]
            + pp[idx + 3 * B_ * DT_];
    bap[idx] = (__hip_bfloat16)s;
}

// ---------------------------------------------------------------------------
// 7. lg[b,k] = y[b,:] @ W_fc[:,k] + b_fc[k]; scatter into out
__global__ void final_kernel(const float* __restrict__ y,
                             const float* __restrict__ Wfc,
                             const float* __restrict__ bfc,
                             const int* __restrict__ topk_idx,
                             float* __restrict__ out) {
    int b = blockIdx.x, tid = threadIdx.x;
    int lane = tid & 63, wave = tid >> 6;
    float pk[K_] = {};
    for (int d = tid; d < DT_; d += 256) {
        float yv = y[(size_t)b * DT_ + d];
        #pragma unroll
        for (int k = 0; k < K_; ++k) pk[k] += yv * Wfc[(size_t)d * K_ + k];
    }
    __shared__ float wsum[4][K_];
    #pragma unroll
    for (int k = 0; k < K_; ++k) {
        float a = pk[k];
        #pragma unroll
        for (int off = 32; off > 0; off >>= 1) a += __shfl_down(a, off);
        if (lane == 0) wsum[wave][k] = a;
    }
    __syncthreads();
    if (tid < K_) {
        float lg = wsum[0][tid] + wsum[1][tid] + wsum[2][tid] + wsum[3][tid] + bfc[tid];
        out[(size_t)b * C_ + topk_idx[b * K_ + tid]] = lg;
    }
}

// ---------------------------------------------------------------------------
extern "C" void kernel_launch(void* const* d_in, const int* in_sizes, int n_in,
                              void* d_out, int out_size, void* d_ws, size_t ws_size,
                              hipStream_t stream) {
    const float* ftm           = (const float*)d_in[0];
    const float* logits        = (const float*)d_in[1];
    const int*   indices_table = (const int*)d_in[3];
    const float* word2vec      = (const float*)d_in[4];
    const float* W_emb         = (const float*)d_in[5];
    const float* b_emb         = (const float*)d_in[6];
    const float* W_cls         = (const float*)d_in[7];
    const float* b_cls         = (const float*)d_in[8];
    const float* W_v           = (const float*)d_in[9];
    const float* b_v           = (const float*)d_in[10];
    const float* W_bap         = (const float*)d_in[11];
    const float* b_bap         = (const float*)d_in[12];
    const float* W_fc          = (const float*)d_in[13];
    const float* b_fc          = (const float*)d_in[14];
    float* out = (float*)d_out;

    char* ws = (char*)d_ws;
    size_t off = 0;
    auto alloc = [&](size_t bytes) -> void* {
        void* p = ws + off;
        off = (off + bytes + 255) & ~(size_t)255;
        return p;
    };
    int*            topk_idx = (int*)           alloc((size_t)B_ * K_ * 4);
    __hip_bfloat16* emb_bf   = (__hip_bfloat16*)alloc((size_t)B_ * K_ * DWP_ * 2);
    __hip_bfloat16* cls1     = (__hip_bfloat16*)alloc((size_t)B_ * K_ * DT_ * 2);
    __hip_bfloat16* cls2     = (__hip_bfloat16*)alloc((size_t)B_ * K_ * DT_ * 2);
    __hip_bfloat16* Wemb_t   = (__hip_bfloat16*)alloc((size_t)DT_ * DWP_ * 2);
    __hip_bfloat16* Wcls_t   = (__hip_bfloat16*)alloc((size_t)DT_ * DT_ * 2);
    __hip_bfloat16* Wv_t     = (__hip_bfloat16*)alloc((size_t)DT_ * DF_ * 2);
    __hip_bfloat16* Wbap_t   = (__hip_bfloat16*)alloc((size_t)DT_ * DT_ * 2);
    float*          s_buf    = (float*)         alloc((size_t)B_ * F_ * K_ * 4);
    float*          attw     = (float*)         alloc((size_t)B_ * F_ * K_ * 4);
    float*          pp       = (float*)         alloc((size_t)NSEG * B_ * DT_ * 4);
    __hip_bfloat16* bap_bf   = (__hip_bfloat16*)alloc((size_t)B_ * DT_ * 2);
    float*          yb       = (float*)         alloc((size_t)B_ * DT_ * 4);

    // dynamic batch-chunk: fit ftm_t + v for nb batches in remaining ws
    size_t per_b = (size_t)F_ * DF_ * 2 + (size_t)F_ * DT_ * 2;
    size_t avail = (ws_size > off + 8192) ? ws_size - off - 8192 : 0;
    int nb = (int)(avail / per_b);
    if (nb > B_) nb = B_;
    if (nb < 1) nb = 1;
    __hip_bfloat16* ftm_t = (__hip_bfloat16*)alloc((size_t)nb * F_ * DF_ * 2);
    __hip_bfloat16* v_buf = (__hip_bfloat16*)alloc((size_t)nb * F_ * DT_ * 2);

    hipMemsetAsync(d_out, 0, (size_t)out_size * sizeof(float), stream);

    topk_kernel<<<B_, 256, 0, stream>>>(logits, topk_idx);
    emb_kernel<<<(B_ * K_ * DWP_ + 255) / 256, 256, 0, stream>>>(
        topk_idx, indices_table, word2vec, emb_bf);

    // weight transposes (fp32 [K][N] -> bf16 [N][Kp])
    transpose_pad_cvt<<<dim3(DT_ / 64, DWP_ / 64, 1), 256, 0, stream>>>(
        W_emb, Wemb_t, DW_, DT_, DWP_, 0, 0);
    transpose_pad_cvt<<<dim3(DT_ / 64, DT_ / 64, 1), 256, 0, stream>>>(
        W_cls, Wcls_t, DT_, DT_, DT_, 0, 0);
    transpose_pad_cvt<<<dim3(DT_ / 64, DF_ / 64, 1), 256, 0, stream>>>(
        W_v, Wv_t, DF_, DT_, DF_, 0, 0);
    transpose_pad_cvt<<<dim3(DT_ / 64, DT_ / 64, 1), 256, 0, stream>>>(
        W_bap, Wbap_t, DT_, DT_, DT_, 0, 0);

    // cls path (MFMA)
    gemm_mfma<1, 1><<<dim3((B_ * K_ + 127) / 128, DT_ / 128), 256, 0, stream>>>(
        emb_bf, Wemb_t, b_emb, cls1, B_ * K_, DT_, DWP_);
    gemm_mfma<1, 1><<<dim3((B_ * K_ + 127) / 128, DT_ / 128), 256, 0, stream>>>(
        cls1, Wcls_t, b_cls, cls2, B_ * K_, DT_, DT_);

    // main path, chunked only if ws is small (nb == 64 -> single pass)
    for (int b0 = 0; b0 < B_; b0 += nb) {
        int cb = min(nb, B_ - b0);
        transpose_pad_cvt<<<dim3((F_ + 63) / 64, DF_ / 64, cb), 256, 0, stream>>>(
            ftm + (size_t)b0 * DF_ * F_, ftm_t, DF_, F_, DF_,
            (size_t)DF_ * F_, (size_t)F_ * DF_);
        int M = cb * F_;
        gemm_mfma<1, 1><<<dim3((M + 127) / 128, DT_ / 128), 256, 0, stream>>>(
            ftm_t, Wv_t, b_v, v_buf, M, DT_, DF_);
        float* s_c = s_buf + (size_t)b0 * F_ * K_;
        float* w_c = attw  + (size_t)b0 * F_ * K_;
        attn_s_kernel<<<dim3(F_ / 4, cb), 256, 0, stream>>>(
            v_buf, cls2, s_c, b0);
        softmax_kernel<<<dim3(K_, cb), 256, 0, stream>>>(s_c, w_c);
        o_bap_partial<<<dim3(cb, NSEG), 256, 0, stream>>>(
            v_buf, w_c, cls2, pp, b0);
    }
    bap_combine<<<B_ * DT_ / 256, 256, 0, stream>>>(pp, bap_bf);

    gemm_mfma<1, 0><<<dim3(1, DT_ / 128), 256, 0, stream>>>(
        bap_bf, Wbap_t, b_bap, yb, B_, DT_, DT_);
    final_kernel<<<B_, 256, 0, stream>>>(yb, W_fc, b_fc, topk_idx, out);
}

// Round 5
// 527.645 us; speedup vs baseline: 4.3149x; 1.1145x over previous
//
#include <hip/hip_runtime.h>
#include <hip/hip_bf16.h>

// Problem constants
#define B_   64
#define C_   3129
#define K_   10
#define DF_  768
#define F_   676      // 26*26
#define DW_  300
#define DWP_ 320      // DW_ padded to multiple of 64 (MFMA K-tile)
#define DT_  1024
#define NSEG 4        // o_bap f-segments: 676 = 4*169
#define FSEG 169

typedef __attribute__((ext_vector_type(8))) short short8;   // 8 bf16
typedef __attribute__((ext_vector_type(4))) float floatx4;  // 4 fp32

// async 16B global -> LDS (wave-uniform LDS base + lane*16)
__device__ __forceinline__ void gload_lds16(const void* g, void* l) {
    __builtin_amdgcn_global_load_lds(
        (const __attribute__((address_space(1))) void*)g,
        (__attribute__((address_space(3))) void*)l, 16, 0, 0);
}

// ---------------------------------------------------------------------------
// 1. top-k (K=10) per row of logits [B, C], exact lax.top_k order.
__global__ void topk_kernel(const float* __restrict__ logits,
                            int* __restrict__ topk_idx) {
    __shared__ float vals[C_];
    __shared__ float red_v[256];
    __shared__ int   red_i[256];
    int b = blockIdx.x;
    int tid = threadIdx.x;
    for (int i = tid; i < C_; i += 256) vals[i] = logits[(size_t)b * C_ + i];
    __syncthreads();
    for (int sel = 0; sel < K_; ++sel) {
        float bv = -INFINITY; int bi = 0x7fffffff;
        for (int i = tid; i < C_; i += 256) {
            float v = vals[i];
            if (v > bv) { bv = v; bi = i; }
        }
        red_v[tid] = bv; red_i[tid] = bi;
        __syncthreads();
        for (int s = 128; s > 0; s >>= 1) {
            if (tid < s) {
                float ov = red_v[tid + s]; int oi = red_i[tid + s];
                if (ov > red_v[tid] || (ov == red_v[tid] && oi < red_i[tid])) {
                    red_v[tid] = ov; red_i[tid] = oi;
                }
            }
            __syncthreads();
        }
        if (tid == 0) {
            topk_idx[b * K_ + sel] = red_i[0];
            vals[red_i[0]] = -INFINITY;
        }
        __syncthreads();
    }
}

// ---------------------------------------------------------------------------
// 2. emb[bk][j] (bf16, K-padded to DWP_ with zeros)
__global__ void emb_kernel(const int* __restrict__ topk_idx,
                           const int* __restrict__ indices_table,
                           const float* __restrict__ word2vec,
                           __hip_bfloat16* __restrict__ emb) {
    int idx = blockIdx.x * blockDim.x + threadIdx.x;
    if (idx >= B_ * K_ * DWP_) return;
    int j  = idx % DWP_;
    int bk = idx / DWP_;
    float s = 0.f;
    if (j < DW_) {
        int cls = topk_idx[bk];
        const int* tbl = indices_table + (size_t)cls * 4;
        #pragma unroll
        for (int i = 0; i < 4; ++i) s += word2vec[(size_t)tbl[i] * DW_ + j];
        s *= 0.25f;
    }
    emb[idx] = (__hip_bfloat16)s;
}

// ---------------------------------------------------------------------------
// Transpose body: src[R][Cc] fp32 -> dst[Cc][Rp] bf16, zero-padded rows >= R.
__device__ __forceinline__ void tp_body(const float* __restrict__ s,
                                        __hip_bfloat16* __restrict__ d,
                                        int R, int Cc, int Rp, int c0, int r0) {
    __shared__ float tile[64][65];
    int t = threadIdx.x;
    int cl = (t & 15) * 4;
    int rl = t >> 4;
    #pragma unroll
    for (int i = 0; i < 4; ++i) {
        int r = rl + i * 16;
        float4 v = make_float4(0.f, 0.f, 0.f, 0.f);
        if (r0 + r < R && c0 + cl < Cc)
            v = *(const float4*)(s + (size_t)(r0 + r) * Cc + c0 + cl);
        tile[r][cl + 0] = v.x; tile[r][cl + 1] = v.y;
        tile[r][cl + 2] = v.z; tile[r][cl + 3] = v.w;
    }
    __syncthreads();
    int cw = t >> 2;
    int r4 = (t & 3) * 16;
    if (c0 + cw < Cc) {
        __align__(16) __hip_bfloat16 buf[16];
        #pragma unroll
        for (int j = 0; j < 16; ++j) buf[j] = (__hip_bfloat16)tile[r4 + j][cw];
        float4* dp = (float4*)(d + (size_t)(c0 + cw) * Rp + r0 + r4);
        dp[0] = *(float4*)&buf[0];
        dp[1] = *(float4*)&buf[8];
    }
}

// ftm transpose (z-batched)
__global__ __launch_bounds__(256)
void transpose_ftm(const float* __restrict__ src, __hip_bfloat16* __restrict__ dst) {
    tp_body(src + (size_t)blockIdx.z * DF_ * F_,
            dst + (size_t)blockIdx.z * F_ * DF_,
            DF_, F_, DF_, blockIdx.x * 64, blockIdx.y * 64);
}

// all 4 weight transposes in one dispatch (tile ranges hard-coded)
// W_emb: 16x5=80 | W_cls: 16x16=256 | W_v: 16x12=192 | W_bap: 256 -> 784
__global__ __launch_bounds__(256)
void transpose_weights(const float* __restrict__ Wemb, __hip_bfloat16* __restrict__ WembT,
                       const float* __restrict__ Wcls, __hip_bfloat16* __restrict__ WclsT,
                       const float* __restrict__ Wv,   __hip_bfloat16* __restrict__ WvT,
                       const float* __restrict__ Wbap, __hip_bfloat16* __restrict__ WbapT) {
    int id = blockIdx.x;
    const float* s; __hip_bfloat16* d; int R, Rp;
    if (id < 80)       { s = Wemb; d = WembT; R = DW_;  Rp = DWP_; }
    else if (id < 336) { s = Wcls; d = WclsT; R = DT_;  Rp = DT_;  id -= 80;  }
    else if (id < 528) { s = Wv;   d = WvT;   R = DF_;  Rp = DF_;  id -= 336; }
    else               { s = Wbap; d = WbapT; R = DT_;  Rp = DT_;  id -= 528; }
    int bx = id & 15;        // Cc = 1024 -> 16 col tiles for all mats
    int by = id >> 4;
    tp_body(s, d, R, DT_, Rp, bx * 64, by * 64);
}

// ---------------------------------------------------------------------------
// MFMA bf16 GEMM: C[M][N] = act(A[M][Kp] @ Bt[N][Kp]^T + bias)
// 128x128 tile, BK=64, global_load_lds w16 with XOR chunk swizzle (bank-free
// fragment reads), coalesced LDS epilogue (OUTBF=1). grid = (N/128, mblocks).
template <int RELU, int OUTBF>
__global__ __launch_bounds__(256)
void gemm_mfma(const __hip_bfloat16* __restrict__ A,
               const __hip_bfloat16* __restrict__ Bt,
               const float* __restrict__ bias,
               void* __restrict__ Cout, int M, int N, int Kp) {
    __shared__ __align__(16) char smem[34816];       // max(As+Bs, C-tile 128x136)
    __hip_bfloat16* As = (__hip_bfloat16*)smem;      // [128][64]
    __hip_bfloat16* Bs = As + 128 * 64;              // [128][64]
    int tid = threadIdx.x;
    int wave = tid >> 6, lane = tid & 63;
    int quad = lane >> 4, l16 = lane & 15;
    int wm = (wave & 1) * 64, wn = (wave >> 1) * 64;
    int n0 = blockIdx.x * 128;
    int m0 = blockIdx.y * 128;

    floatx4 acc[4][4];
    #pragma unroll
    for (int i = 0; i < 4; ++i)
        #pragma unroll
        for (int j = 0; j < 4; ++j)
            acc[i][j] = (floatx4){0.f, 0.f, 0.f, 0.f};

    // staging: group g = wave*4+c covers LDS rows [g*8, g*8+8) (1024 B).
    // lane l: row sub l>>3, LDS chunk q = l&7; global chunk = q ^ rsub (swizzle
    // inverted on the global side so LDS dest stays lane-linear).
    int rsub = lane >> 3;
    int gchunk = (lane & 7) ^ rsub;

    // fragment row bases (precomputed)
    int arow[4], brow[4];
    #pragma unroll
    for (int i = 0; i < 4; ++i) {
        arow[i] = wm + i * 16 + l16;
        brow[i] = wn + i * 16 + l16;
    }

    for (int k0 = 0; k0 < Kp; k0 += 64) {
        #pragma unroll
        for (int c = 0; c < 4; ++c) {
            int grp = wave * 4 + c;
            int row = grp * 8 + rsub;
            int ra = m0 + row; if (ra >= M) ra = M - 1;   // clamp: junk unused
            gload_lds16(A + (size_t)ra * Kp + k0 + gchunk * 8, As + grp * 512);
            gload_lds16(Bt + (size_t)(n0 + row) * Kp + k0 + gchunk * 8, Bs + grp * 512);
        }
        __syncthreads();
        #pragma unroll
        for (int ks = 0; ks < 2; ++ks) {
            short8 af[4], bf[4];
            #pragma unroll
            for (int mi = 0; mi < 4; ++mi)
                af[mi] = *(const short8*)&As[arow[mi] * 64 +
                            ((((ks << 2) | quad) ^ (arow[mi] & 7)) << 3)];
            #pragma unroll
            for (int ni = 0; ni < 4; ++ni)
                bf[ni] = *(const short8*)&Bs[brow[ni] * 64 +
                            ((((ks << 2) | quad) ^ (brow[ni] & 7)) << 3)];
            #pragma unroll
            for (int mi = 0; mi < 4; ++mi)
                #pragma unroll
                for (int ni = 0; ni < 4; ++ni)
                    acc[mi][ni] = __builtin_amdgcn_mfma_f32_16x16x32_bf16(
                        af[mi], bf[ni], acc[mi][ni], 0, 0, 0);
        }
        __syncthreads();
    }

    // C/D mapping: col = lane&15, row = quad*4 + reg  [measured m89/m91]
    float bn[4];
    #pragma unroll
    for (int ni = 0; ni < 4; ++ni) bn[ni] = bias[n0 + wn + ni * 16 + l16];

    if (OUTBF) {
        // stage tile in LDS (stride 136 bf16 = 272 B, 16B-aligned rows)
        __hip_bfloat16* Cs = (__hip_bfloat16*)smem;
        #pragma unroll
        for (int mi = 0; mi < 4; ++mi)
            #pragma unroll
            for (int rr = 0; rr < 4; ++rr) {
                int row = wm + mi * 16 + quad * 4 + rr;
                #pragma unroll
                for (int ni = 0; ni < 4; ++ni) {
                    float val = acc[mi][ni][rr] + bn[ni];
                    if (RELU) val = fmaxf(val, 0.f);
                    Cs[row * 136 + wn + ni * 16 + l16] = (__hip_bfloat16)val;
                }
            }
        __syncthreads();
        #pragma unroll
        for (int j = 0; j < 8; ++j) {
            int ch = tid + 256 * j;              // 2048 chunks of 16 B
            int row = ch >> 4, c16 = ch & 15;
            int r = m0 + row;
            float4 val = *(const float4*)&Cs[row * 136 + c16 * 8];
            if (r < M)
                *(float4*)((__hip_bfloat16*)Cout + (size_t)r * N + n0 + c16 * 8) = val;
        }
    } else {
        #pragma unroll
        for (int mi = 0; mi < 4; ++mi)
            #pragma unroll
            for (int rr = 0; rr < 4; ++rr) {
                int r = m0 + wm + mi * 16 + quad * 4 + rr;
                if (r < M) {
                    #pragma unroll
                    for (int ni = 0; ni < 4; ++ni) {
                        float val = acc[mi][ni][rr] + bn[ni];
                        if (RELU) val = fmaxf(val, 0.f);
                        ((float*)Cout)[(size_t)r * N + n0 + wn + ni * 16 + l16] = val;
                    }
                }
            }
    }
}

// ---------------------------------------------------------------------------
// 4. s[bc,f,k] = sum_d v[bc,f,d] * cls[b0+bc,k,d]; 2 f per wave (halves cls
//    L2 traffic).
__global__ __launch_bounds__(256)
void attn_s_kernel(const __hip_bfloat16* __restrict__ v_buf,
                   const __hip_bfloat16* __restrict__ cls,
                   float* __restrict__ s_buf, int b0) {
    int tid = threadIdx.x;
    int wave = tid >> 6, lane = tid & 63;
    int bc = blockIdx.y;
    int f0 = blockIdx.x * 8 + wave * 2;     // 85 blocks cover 680 >= 676
    int fa = f0 < F_ ? f0 : F_ - 1;
    int fb = (f0 + 1) < F_ ? f0 + 1 : F_ - 1;
    union U { float4 f4; __hip_bfloat16 h[8]; };
    const float4* va = (const float4*)(v_buf + ((size_t)(bc * F_ + fa)) * DT_ + lane * 16);
    const float4* vb = (const float4*)(v_buf + ((size_t)(bc * F_ + fb)) * DT_ + lane * 16);
    U a0, a1, b0u, b1u;
    a0.f4 = va[0]; a1.f4 = va[1];
    b0u.f4 = vb[0]; b1u.f4 = vb[1];
    float av[16], bv[16];
    #pragma unroll
    for (int i = 0; i < 8; ++i) {
        av[i] = (float)a0.h[i]; av[8 + i] = (float)a1.h[i];
        bv[i] = (float)b0u.h[i]; bv[8 + i] = (float)b1u.h[i];
    }
    const __hip_bfloat16* cp = cls + ((size_t)(b0 + bc) * K_) * DT_ + lane * 16;
    #pragma unroll
    for (int k = 0; k < K_; ++k) {
        const float4* c4 = (const float4*)(cp + (size_t)k * DT_);
        U c0u, c1u; c0u.f4 = c4[0]; c1u.f4 = c4[1];
        float da = 0.f, db = 0.f;
        #pragma unroll
        for (int i = 0; i < 8; ++i) {
            float cl0 = (float)c0u.h[i], cl1 = (float)c1u.h[i];
            da += av[i] * cl0 + av[8 + i] * cl1;
            db += bv[i] * cl0 + bv[8 + i] * cl1;
        }
        #pragma unroll
        for (int off = 32; off > 0; off >>= 1) {
            da += __shfl_down(da, off);
            db += __shfl_down(db, off);
        }
        if (lane == 0) {
            if (f0 < F_)     s_buf[((size_t)(bc * F_) + f0) * K_ + k] = da;
            if (f0 + 1 < F_) s_buf[((size_t)(bc * F_) + f0 + 1) * K_ + k] = db;
        }
    }
}

// ---------------------------------------------------------------------------
// 5. softmax stats per (bc,k): m = max_f s, rl = 1/sum_f exp(s-m)
__global__ __launch_bounds__(64)
void softmax_stats(const float* __restrict__ s_buf, float2* __restrict__ ml,
                   int b0) {
    int k = blockIdx.x, bc = blockIdx.y, lane = threadIdx.x;
    const float* sp = s_buf + (size_t)bc * F_ * K_ + k;
    float m = -INFINITY;
    for (int f = lane; f < F_; f += 64) m = fmaxf(m, sp[(size_t)f * K_]);
    #pragma unroll
    for (int off = 32; off > 0; off >>= 1) m = fmaxf(m, __shfl_xor(m, off));
    float l = 0.f;
    for (int f = lane; f < F_; f += 64) l += __expf(sp[(size_t)f * K_] - m);
    #pragma unroll
    for (int off = 32; off > 0; off >>= 1) l += __shfl_xor(l, off);
    if (lane == 0) ml[(size_t)(b0 + bc) * K_ + k] = make_float2(m, 1.f / l);
}

// ---------------------------------------------------------------------------
// 6a. partial bap over f-segment, softmax weights computed inline:
//     pp[seg][b][d] = sum_k cls[b,k,d] * sum_{f in seg} w[f,k]*v[bc,f,d]
__global__ __launch_bounds__(256)
void o_bap_partial(const __hip_bfloat16* __restrict__ v_buf,
                   const float* __restrict__ s_buf,
                   const float2* __restrict__ ml,
                   const __hip_bfloat16* __restrict__ cls,
                   float* __restrict__ pp, int b0) {
    int bc = blockIdx.x, seg = blockIdx.y;
    int b = b0 + bc;
    int t = threadIdx.x;
    int f0 = seg * FSEG;
    __shared__ float wbuf[FSEG * K_];
    __shared__ float mk[K_], rlk[K_];
    if (t < K_) {
        float2 v = ml[(size_t)b * K_ + t];
        mk[t] = v.x; rlk[t] = v.y;
    }
    __syncthreads();
    for (int j = t; j < FSEG * K_; j += 256) {
        int k = j % K_;
        float sv = s_buf[((size_t)bc * F_ + f0) * K_ + j];
        wbuf[j] = __expf(sv - mk[k]) * rlk[k];
    }
    __syncthreads();
    int d0 = t * 4;
    float acc[K_][4] = {};
    const __hip_bfloat16* vp = v_buf + ((size_t)bc * F_ + f0) * DT_ + d0;
    for (int f = 0; f < FSEG; ++f) {
        union { float2 f2; __hip_bfloat16 h[4]; } u;
        u.f2 = *(const float2*)(vp + (size_t)f * DT_);
        float vv[4];
        #pragma unroll
        for (int i = 0; i < 4; ++i) vv[i] = (float)u.h[i];
        const float* wk = &wbuf[f * K_];
        #pragma unroll
        for (int k = 0; k < K_; ++k)
            #pragma unroll
            for (int i = 0; i < 4; ++i) acc[k][i] += wk[k] * vv[i];
    }
    union { float2 f2; __hip_bfloat16 h[4]; } cu;
    float outv[4] = {};
    #pragma unroll
    for (int k = 0; k < K_; ++k) {
        cu.f2 = *(const float2*)(cls + ((size_t)b * K_ + k) * DT_ + d0);
        #pragma unroll
        for (int i = 0; i < 4; ++i) outv[i] += acc[k][i] * (float)cu.h[i];
    }
    float* pd = pp + ((size_t)seg * B_ + b) * DT_ + d0;
    *(float4*)pd = *(float4*)outv;
}

// 6b. combine segments -> bf16 bap
__global__ void bap_combine(const float* __restrict__ pp,
                            __hip_bfloat16* __restrict__ bap) {
    int idx = blockIdx.x * 256 + threadIdx.x;   // B_*DT_ total
    float s = pp[idx] + pp[idx + B_ * DT_] + pp[idx + 2 * B_ * DT_]
            + pp[idx + 3 * B_ * DT_];
    bap[idx] = (__hip_bfloat16)s;
}

// ---------------------------------------------------------------------------
// 7. lg[b,k] = y[b,:] @ W_fc[:,k] + b_fc[k]; scatter into out
__global__ void final_kernel(const float* __restrict__ y,
                             const float* __restrict__ Wfc,
                             const float* __restrict__ bfc,
                             const int* __restrict__ topk_idx,
                             float* __restrict__ out) {
    int b = blockIdx.x, tid = threadIdx.x;
    int lane = tid & 63, wave = tid >> 6;
    float pk[K_] = {};
    for (int d = tid; d < DT_; d += 256) {
        float yv = y[(size_t)b * DT_ + d];
        #pragma unroll
        for (int k = 0; k < K_; ++k) pk[k] += yv * Wfc[(size_t)d * K_ + k];
    }
    __shared__ float wsum[4][K_];
    #pragma unroll
    for (int k = 0; k < K_; ++k) {
        float a = pk[k];
        #pragma unroll
        for (int off = 32; off > 0; off >>= 1) a += __shfl_down(a, off);
        if (lane == 0) wsum[wave][k] = a;
    }
    __syncthreads();
    if (tid < K_) {
        float lg = wsum[0][tid] + wsum[1][tid] + wsum[2][tid] + wsum[3][tid] + bfc[tid];
        out[(size_t)b * C_ + topk_idx[b * K_ + tid]] = lg;
    }
}

// ---------------------------------------------------------------------------
extern "C" void kernel_launch(void* const* d_in, const int* in_sizes, int n_in,
                              void* d_out, int out_size, void* d_ws, size_t ws_size,
                              hipStream_t stream) {
    const float* ftm           = (const float*)d_in[0];
    const float* logits        = (const float*)d_in[1];
    const int*   indices_table = (const int*)d_in[3];
    const float* word2vec      = (const float*)d_in[4];
    const float* W_emb         = (const float*)d_in[5];
    const float* b_emb         = (const float*)d_in[6];
    const float* W_cls         = (const float*)d_in[7];
    const float* b_cls         = (const float*)d_in[8];
    const float* W_v           = (const float*)d_in[9];
    const float* b_v           = (const float*)d_in[10];
    const float* W_bap         = (const float*)d_in[11];
    const float* b_bap         = (const float*)d_in[12];
    const float* W_fc          = (const float*)d_in[13];
    const float* b_fc          = (const float*)d_in[14];
    float* out = (float*)d_out;

    char* ws = (char*)d_ws;
    size_t off = 0;
    auto alloc = [&](size_t bytes) -> void* {
        void* p = ws + off;
        off = (off + bytes + 255) & ~(size_t)255;
        return p;
    };
    int*            topk_idx = (int*)           alloc((size_t)B_ * K_ * 4);
    __hip_bfloat16* emb_bf   = (__hip_bfloat16*)alloc((size_t)B_ * K_ * DWP_ * 2);
    __hip_bfloat16* cls1     = (__hip_bfloat16*)alloc((size_t)B_ * K_ * DT_ * 2);
    __hip_bfloat16* cls2     = (__hip_bfloat16*)alloc((size_t)B_ * K_ * DT_ * 2);
    __hip_bfloat16* Wemb_t   = (__hip_bfloat16*)alloc((size_t)DT_ * DWP_ * 2);
    __hip_bfloat16* Wcls_t   = (__hip_bfloat16*)alloc((size_t)DT_ * DT_ * 2);
    __hip_bfloat16* Wv_t     = (__hip_bfloat16*)alloc((size_t)DT_ * DF_ * 2);
    __hip_bfloat16* Wbap_t   = (__hip_bfloat16*)alloc((size_t)DT_ * DT_ * 2);
    float*          s_buf    = (float*)         alloc((size_t)B_ * F_ * K_ * 4);
    float2*         ml       = (float2*)        alloc((size_t)B_ * K_ * 8);
    float*          pp       = (float*)         alloc((size_t)NSEG * B_ * DT_ * 4);
    __hip_bfloat16* bap_bf   = (__hip_bfloat16*)alloc((size_t)B_ * DT_ * 2);
    float*          yb       = (float*)         alloc((size_t)B_ * DT_ * 4);

    // dynamic batch-chunk: fit ftm_t + v for nb batches in remaining ws
    size_t per_b = (size_t)F_ * DF_ * 2 + (size_t)F_ * DT_ * 2;
    size_t avail = (ws_size > off + 8192) ? ws_size - off - 8192 : 0;
    int nb = (int)(avail / per_b);
    if (nb > B_) nb = B_;
    if (nb < 1) nb = 1;
    __hip_bfloat16* ftm_t = (__hip_bfloat16*)alloc((size_t)nb * F_ * DF_ * 2);
    __hip_bfloat16* v_buf = (__hip_bfloat16*)alloc((size_t)nb * F_ * DT_ * 2);

    hipMemsetAsync(d_out, 0, (size_t)out_size * sizeof(float), stream);

    topk_kernel<<<B_, 256, 0, stream>>>(logits, topk_idx);
    emb_kernel<<<(B_ * K_ * DWP_ + 255) / 256, 256, 0, stream>>>(
        topk_idx, indices_table, word2vec, emb_bf);

    transpose_weights<<<784, 256, 0, stream>>>(
        W_emb, Wemb_t, W_cls, Wcls_t, W_v, Wv_t, W_bap, Wbap_t);

    // cls path (MFMA, n-fastest grid)
    gemm_mfma<1, 1><<<dim3(DT_ / 128, (B_ * K_ + 127) / 128), 256, 0, stream>>>(
        emb_bf, Wemb_t, b_emb, cls1, B_ * K_, DT_, DWP_);
    gemm_mfma<1, 1><<<dim3(DT_ / 128, (B_ * K_ + 127) / 128), 256, 0, stream>>>(
        cls1, Wcls_t, b_cls, cls2, B_ * K_, DT_, DT_);

    // main path, chunked only if ws is small (nb == 64 -> single pass)
    for (int b0 = 0; b0 < B_; b0 += nb) {
        int cb = min(nb, B_ - b0);
        transpose_ftm<<<dim3((F_ + 63) / 64, DF_ / 64, cb), 256, 0, stream>>>(
            ftm + (size_t)b0 * DF_ * F_, ftm_t);
        int M = cb * F_;
        gemm_mfma<1, 1><<<dim3(DT_ / 128, (M + 127) / 128), 256, 0, stream>>>(
            ftm_t, Wv_t, b_v, v_buf, M, DT_, DF_);
        float* s_c = s_buf + (size_t)b0 * F_ * K_;
        attn_s_kernel<<<dim3((F_ + 7) / 8, cb), 256, 0, stream>>>(
            v_buf, cls2, s_c, b0);
        softmax_stats<<<dim3(K_, cb), 64, 0, stream>>>(s_c, ml, b0);
        o_bap_partial<<<dim3(cb, NSEG), 256, 0, stream>>>(
            v_buf, s_c, ml, cls2, pp, b0);
    }
    bap_combine<<<B_ * DT_ / 256, 256, 0, stream>>>(pp, bap_bf);

    gemm_mfma<1, 0><<<dim3(DT_ / 128, 1), 256, 0, stream>>>(
        bap_bf, Wbap_t, b_bap, yb, B_, DT_, DT_);
    final_kernel<<<B_, 256, 0, stream>>>(yb, W_fc, b_fc, topk_idx, out);
}